// Round 12
// baseline (300.653 us; speedup 1.0000x reference)
//
#include <hip/hip_runtime.h>

// Problem constants (fixed by the reference)
#define NN     100000      // nodes
#define EE     1600000     // edges
#define NB     8           // graphs
#define BLK    12500       // nodes per graph
#define HID    128
#define KC     4
#define CHUNKS 196         // ceil(12500/64)
#define NTILE  49          // dst-ranges of 256 nodes per graph
#define NBIN   392         // 8 graphs x 49 tiles
#define GCAPS  5120        // per-bin capacity (mean 4081, sigma ~64)

typedef __attribute__((ext_vector_type(8))) short bf16x8;
typedef __attribute__((ext_vector_type(4))) float f32x4;

__device__ __forceinline__ ushort f2bf(float f) {
  uint u = __float_as_uint(f);
  return (ushort)((u + 0x7FFFu + ((u >> 16) & 1u)) >> 16);  // RNE
}
__device__ __forceinline__ float bf2f(ushort h) {
  return __uint_as_float(((uint)h) << 16);
}

// ---------------------------------------------------------------- K0a: x -> bf16
__global__ __launch_bounds__(256) void k_prep_x(const float4* __restrict__ x4,
                                                ushort* __restrict__ xb) {
  int i = blockIdx.x * 256 + threadIdx.x;  // 3.2M float4s exactly
  float4 v = x4[i];
  ushort4 r;
  r.x = f2bf(v.x); r.y = f2bf(v.y); r.z = f2bf(v.z); r.w = f2bf(v.w);
  *(ushort4*)(xb + (size_t)i * 4) = r;
}

// ---------------------------------------------------------------- K0b: Wt[col][k], k<128 = Wrel1, k>=128 = Wroot1
__global__ __launch_bounds__(256) void k_prep_w(const float* __restrict__ Wrel1,
                                                const float* __restrict__ Wroot1,
                                                ushort* __restrict__ Wt) {
  int col = blockIdx.x, k = threadIdx.x;
  float v = (k < 128) ? Wrel1[k * 128 + col] : Wroot1[(k - 128) * 128 + col];
  Wt[col * 256 + k] = f2bf(v);
}

// ---------------------------------------------------------------- K1a: edges -> 392 (graph, dst-range) sub-buckets
// gfx950 L2 does NOT write-allocate on store miss (R3/R6) -> isolated
// scattered stores cost a partial line each. Stage 8192 edges in LDS, sort
// by bin, flush per-bin contiguous runs.
__global__ __launch_bounds__(256) void k_bucket2(const int* __restrict__ ei,
                                                 int* __restrict__ sbcnt,
                                                 uint* __restrict__ gbuf) {
  __shared__ uint stage[8192];
  __shared__ int cnt[NBIN], start[NBIN + 1], rbase[NBIN];
  __shared__ int gtot[8], gb[8];
  const int t = threadIdx.x;
  for (int b = t; b < NBIN; b += 256) cnt[b] = 0;
  __syncthreads();
  const int e0 = blockIdx.x * 8192;
  uint pk[32]; int br[32];
#pragma unroll
  for (int i = 0; i < 32; ++i) {
    int e = e0 + i * 256 + t;
    bool val = (e < EE);
    int src = 0, dst = 0;
    if (val) {
      src = __builtin_nontemporal_load(ei + e);
      dst = __builtin_nontemporal_load(ei + EE + e);
    }
    int g = dst / BLK;
    int dl = dst - g * BLK;
    int sl = src - g * BLK;
    int bin = g * NTILE + (dl >> 8);
    pk[i] = ((uint)sl << 16) | (uint)dl;
    br[i] = val ? ((bin << 14) | atomicAdd(&cnt[bin], 1)) : -1;
  }
  __syncthreads();
  if (t < 8) {
    int s = 0;
    for (int k = 0; k < NTILE; ++k) s += cnt[t * NTILE + k];
    gtot[t] = s;
  }
  __syncthreads();
  if (t == 0) {
    int s = 0;
    for (int g = 0; g < 8; ++g) { gb[g] = s; s += gtot[g]; }
    start[NBIN] = s;
  }
  __syncthreads();
  if (t < 8) {
    int run = gb[t];
    for (int k = 0; k < NTILE; ++k) { start[t * NTILE + k] = run; run += cnt[t * NTILE + k]; }
  }
  __syncthreads();
  for (int b = t; b < NBIN; b += 256) rbase[b] = atomicAdd(&sbcnt[b], cnt[b]);
#pragma unroll
  for (int i = 0; i < 32; ++i) {
    if (br[i] >= 0) {
      int bin = br[i] >> 14, rank = br[i] & 16383;
      stage[start[bin] + rank] = pk[i];
    }
  }
  __syncthreads();
  const int total = start[NBIN];
  for (int j = t; j < total; j += 256) {
    int lo = 0, hi = NBIN - 1;  // largest bin with start[bin] <= j
    while (lo < hi) { int mid = (lo + hi + 1) >> 1; if (j >= start[mid]) lo = mid; else hi = mid - 1; }
    gbuf[(size_t)lo * GCAPS + rbase[lo] + (j - start[lo])] = stage[j];
  }
}

// ---------------------------------------------------------------- K1b: exclusive scan of bin sizes
__global__ __launch_bounds__(512) void k_scan392(const int* __restrict__ sbcnt,
                                                 int* __restrict__ sbbase) {
  __shared__ int sd[512];
  const int t = threadIdx.x;
  int v = (t < NBIN) ? sbcnt[t] : 0;
  sd[t] = v;
  __syncthreads();
  for (int s = 1; s < 512; s <<= 1) {
    int x = (t >= s) ? sd[t - s] : 0;
    __syncthreads();
    sd[t] += x;
    __syncthreads();
  }
  if (t < NBIN) sbbase[t] = sd[t] - v;
}

// ---------------------------------------------------------------- K1c: per-bin LDS counting sort -> dense CSR segment + rowptr + count
__global__ __launch_bounds__(256) void k_csr_tile(const uint* __restrict__ gbuf,
                                                  const int* __restrict__ sbcnt,
                                                  const int* __restrict__ sbbase,
                                                  int* __restrict__ rowptr,
                                                  int* __restrict__ count,
                                                  int* __restrict__ csr) {
  const int g = blockIdx.x & 7;     // XCD-local per graph
  const int tile = blockIdx.x >> 3; // 0..48
  const int bin = g * NTILE + tile;
  const int m = sbcnt[bin];
  const int base = sbbase[bin];
  const int n0t = tile * 256;
  const int nt = min(256, BLK - n0t);
  __shared__ uint ent[GCAPS];
  __shared__ ushort srt[GCAPS];
  __shared__ int cnt[256], scn[256], cur[256];
  const int t = threadIdx.x;
  cnt[t] = 0;
  __syncthreads();
  const uint* buf = gbuf + (size_t)bin * GCAPS;
  for (int i = t; i < m; i += 256) {
    uint pk = buf[i];
    ent[i] = pk;
    atomicAdd(&cnt[(int)(pk & 0xFFFFu) - n0t], 1);
  }
  __syncthreads();
  int v = cnt[t];
  scn[t] = v;
  __syncthreads();
  for (int s = 1; s < 256; s <<= 1) {
    int x = (t >= s) ? scn[t - s] : 0;
    __syncthreads();
    scn[t] += x;
    __syncthreads();
  }
  int excl = scn[t] - v;
  cur[t] = excl;
  if (t < nt) {
    rowptr[g * BLK + n0t + t] = base + excl;
    count[g * BLK + n0t + t] = v;
  }
  __syncthreads();
  for (int i = t; i < m; i += 256) {
    uint pk = ent[i];
    int p = atomicAdd(&cur[(int)(pk & 0xFFFFu) - n0t], 1);
    srt[p] = (ushort)(pk >> 16);
  }
  __syncthreads();
  const int nb = g * BLK;
  for (int i = t; i < m; i += 256)
    csr[base + i] = nb + (int)srt[i];  // dense coalesced
}

// ---------------------------------------------------------------- K3: FUSED gather + MFMA GEMM + softmax + partial reductions
// R12: k_fused was HBM-LATENCY-bound on aggb reads (FETCH 25.8 MB = aggb;
// no-write-allocate means k_agg2's output lived in HBM; measured MLP ~1.2
// loads/wave). Fix: aggb is DELETED. Each block gathers its 64 nodes' agg
// rows into LDS directly (k_agg2's half-wave-per-node pattern), reading xb
// which IS L2-resident via the XCD mapping g=bi&7 (each XCD caches one
// graph's 3.2 MB x-slice + 0.8 MB csr). GEMM: agg-half from LDS ([64][136]
// ushort, 272 B stride = bank-floor for b128), x-half + B direct from L2.
__global__ __launch_bounds__(256) void k_fused(
    const ushort* __restrict__ xb, const ushort* __restrict__ Wt,
    const float* __restrict__ brel1, const float* __restrict__ Wpool,
    const float* __restrict__ bpool, const int* __restrict__ count,
    const int* __restrict__ rowptr, const int* __restrict__ csr,
    float* __restrict__ s_out, float* __restrict__ pout,
    float* __restrict__ pss, float* __restrict__ pden) {
  __shared__ ushort Asw[64][136];   // agg tile bf16 (stride 272 B)
  __shared__ ushort hLb[64][136];   // h tile bf16
  __shared__ float outL[KC][HID];
  __shared__ float ssL[16];
  __shared__ float denL;

  const int t = threadIdx.x;
  const int bi = blockIdx.x;
  const int bG = bi & 7;            // graph = XCD (blockIdx%8 round-robin)
  const int chunk = bi >> 3;        // 0..195
  const int node0 = bG * BLK + chunk * 64;
  int nrows = BLK - chunk * 64;
  if (nrows > 64) nrows = 64;

  for (int i = t; i < KC * HID; i += 256) ((float*)outL)[i] = 0.f;
  if (t < 16) ssL[t] = 0.f;
  if (t == 0) denL = 0.f;

  // ---- phase 1: gather agg rows into LDS (half-wave per node) ----
  {
    const int half = t >> 5;
    const int lane = t & 31;
#pragma unroll 1
    for (int pass = 0; pass < 8; ++pass) {
      const int ln = pass * 8 + half;  // 0..63
      const bool valid = ln < nrows;
      const int node = node0 + (valid ? ln : 0);
      const int deg = valid ? count[node] : 0;
      const int* sl = csr + rowptr[node];
      int idx0 = (lane < deg) ? sl[lane] : 0;
      int idx1 = (32 + lane < deg) ? sl[32 + lane] : 0;
      float a0 = 0.f, a1 = 0.f, a2 = 0.f, a3 = 0.f;
      for (int e = 0; e < deg; ++e) {
        int srcn = (e < 32) ? __shfl(idx0, e, 32)
                            : ((e < 64) ? __shfl(idx1, e - 32, 32) : sl[e]);
        ushort4 v = *(const ushort4*)(xb + (size_t)srcn * HID + lane * 4);
        a0 += bf2f(v.x); a1 += bf2f(v.y); a2 += bf2f(v.z); a3 += bf2f(v.w);
      }
      ushort4 r;
      r.x = f2bf(a0); r.y = f2bf(a1); r.z = f2bf(a2); r.w = f2bf(a3);
      *(ushort4*)&Asw[ln][lane * 4] = r;
    }
  }
  __syncthreads();

  // ---- phase 2: GEMM ----
  const int w = t >> 6;     // wave: cols 32w..32w+31
  const int l = t & 63;
  const int m16 = l & 15;
  const int gq = l >> 4;

  bf16x8 Breg[8][2];
#pragma unroll
  for (int kt = 0; kt < 8; ++kt)
#pragma unroll
    for (int fc = 0; fc < 2; ++fc)
      Breg[kt][fc] =
          *(const bf16x8*)(Wt + (size_t)(32 * w + 16 * fc + m16) * 256 + kt * 32 + 8 * gq);

  const ushort* Arow_x[4];
#pragma unroll
  for (int fr = 0; fr < 4; ++fr) {
    int r = 16 * fr + m16;
    if (r >= nrows) r = nrows - 1;
    Arow_x[fr] = xb + (size_t)(node0 + r) * HID + 8 * gq;
  }

  f32x4 acc[4][2];
#pragma unroll
  for (int fr = 0; fr < 4; ++fr)
#pragma unroll
    for (int fc = 0; fc < 2; ++fc) acc[fr][fc] = (f32x4){0.f, 0.f, 0.f, 0.f};

#pragma unroll
  for (int kt = 0; kt < 8; ++kt) {
    bf16x8 af[4];
    if (kt < 4) {
#pragma unroll
      for (int fr = 0; fr < 4; ++fr)
        af[fr] = *(const bf16x8*)&Asw[16 * fr + m16][(kt * 4 + gq) * 8];
    } else {
      const int off = (kt & 3) * 32;
#pragma unroll
      for (int fr = 0; fr < 4; ++fr)
        af[fr] = *(const bf16x8*)(Arow_x[fr] + off);
    }
#pragma unroll
    for (int fr = 0; fr < 4; ++fr)
#pragma unroll
      for (int fc = 0; fc < 2; ++fc)
        acc[fr][fc] = __builtin_amdgcn_mfma_f32_16x16x32_bf16(af[fr], Breg[kt][fc],
                                                              acc[fr][fc], 0, 0, 0);
  }

  // bias + relu -> hLb (bf16)  (D layout: row = 4*(l>>4)+reg, col = l&15 [m89])
  const float bc0 = brel1[32 * w + m16];
  const float bc1 = brel1[32 * w + 16 + m16];
#pragma unroll
  for (int fr = 0; fr < 4; ++fr)
#pragma unroll
    for (int fc = 0; fc < 2; ++fc)
#pragma unroll
      for (int r = 0; r < 4; ++r)
        hLb[16 * fr + 4 * gq + r][32 * w + 16 * fc + m16] =
            f2bf(fmaxf(acc[fr][fc][r] + (fc ? bc1 : bc0), 0.f));
  __syncthreads();

  // ---- epilogue (16-lane groups own 4 rows each) ----
  const int g4 = t >> 4;
  const int c0 = (t & 15) << 2;
  const int li = t & 15;

  float h[4][8];
#pragma unroll
  for (int r = 0; r < 4; ++r) {
    ushort4 v0 = *(const ushort4*)&hLb[g4 * 4 + r][c0];
    ushort4 v1 = *(const ushort4*)&hLb[g4 * 4 + r][c0 + 64];
    h[r][0] = bf2f(v0.x); h[r][1] = bf2f(v0.y); h[r][2] = bf2f(v0.z); h[r][3] = bf2f(v0.w);
    h[r][4] = bf2f(v1.x); h[r][5] = bf2f(v1.y); h[r][6] = bf2f(v1.z); h[r][7] = bf2f(v1.w);
  }

  // pooling head: p = h @ Wpool
  float wp[8][4];
#pragma unroll
  for (int j = 0; j < 8; ++j) {
    int col = c0 + (j & 3) + (j >> 2) * 64;
    float4 v = *(const float4*)(Wpool + col * 4);
    wp[j][0] = v.x; wp[j][1] = v.y; wp[j][2] = v.z; wp[j][3] = v.w;
  }
  float pp[4][4];
#pragma unroll
  for (int r = 0; r < 4; ++r)
#pragma unroll
    for (int k = 0; k < 4; ++k) pp[r][k] = 0.f;
#pragma unroll
  for (int r = 0; r < 4; ++r)
#pragma unroll
    for (int j = 0; j < 8; ++j)
#pragma unroll
      for (int k = 0; k < 4; ++k) pp[r][k] = fmaf(h[r][j], wp[j][k], pp[r][k]);
#pragma unroll
  for (int m = 1; m <= 8; m <<= 1)
#pragma unroll
    for (int r = 0; r < 4; ++r)
#pragma unroll
      for (int k = 0; k < 4; ++k) pp[r][k] += __shfl_xor(pp[r][k], m);

  float4 bp4 = *(const float4*)bpool;
  float bp[4] = {bp4.x, bp4.y, bp4.z, bp4.w};
  float sv[4][4];
#pragma unroll
  for (int r = 0; r < 4; ++r) {
    float p[4];
#pragma unroll
    for (int k = 0; k < 4; ++k) p[k] = pp[r][k] + bp[k];
    float mx = fmaxf(fmaxf(p[0], p[1]), fmaxf(p[2], p[3]));
    float e0 = expf(p[0] - mx), e1 = expf(p[1] - mx), e2 = expf(p[2] - mx), e3 = expf(p[3] - mx);
    float inv = 1.f / (e0 + e1 + e2 + e3);
    float valid = (g4 * 4 + r < nrows) ? 1.f : 0.f;
    sv[r][0] = e0 * inv * valid; sv[r][1] = e1 * inv * valid;
    sv[r][2] = e2 * inv * valid; sv[r][3] = e3 * inv * valid;
  }

  // write s
  {
    int rW = li >> 2, kW = li & 3;
    if (g4 * 4 + rW < nrows) {
      int node = node0 + g4 * 4 + rW;
      float val = 0.f;
#pragma unroll
      for (int rr = 0; rr < 4; ++rr)
#pragma unroll
        for (int kk = 0; kk < 4; ++kk)
          if (li == rr * 4 + kk) val = sv[rr][kk];
      s_out[node * 4 + kW] = val;
    }
  }

  // ss[b][k1][k2]
  {
    int k1 = li >> 2, k2 = li & 3;
    float a1[4], a2[4];
#pragma unroll
    for (int rr = 0; rr < 4; ++rr) {
      float v1 = 0.f, v2 = 0.f;
#pragma unroll
      for (int kk = 0; kk < 4; ++kk) {
        if (k1 == kk) v1 = sv[rr][kk];
        if (k2 == kk) v2 = sv[rr][kk];
      }
      a1[rr] = v1; a2[rr] = v2;
    }
    float ssv = a1[0] * a2[0] + a1[1] * a2[1] + a1[2] * a2[2] + a1[3] * a2[3];
    atomicAdd(&ssL[li], ssv);
  }

  // den += deg * ||s||^2
  if (li == 0) {
    float dent = 0.f;
#pragma unroll
    for (int rr = 0; rr < 4; ++rr) {
      int rowg = g4 * 4 + rr;
      if (rowg < nrows) {
        float dg = (float)count[node0 + rowg];
        dent += dg * (sv[rr][0] * sv[rr][0] + sv[rr][1] * sv[rr][1] +
                      sv[rr][2] * sv[rr][2] + sv[rr][3] * sv[rr][3]);
      }
    }
    atomicAdd(&denL, dent);
  }

  // out[k][c] += s[r][k]*h[r][c]
  float po[4][8];
#pragma unroll
  for (int k = 0; k < 4; ++k)
#pragma unroll
    for (int c = 0; c < 8; ++c) po[k][c] = 0.f;
#pragma unroll
  for (int k = 0; k < 4; ++k)
#pragma unroll
    for (int rr = 0; rr < 4; ++rr)
#pragma unroll
      for (int c = 0; c < 8; ++c) po[k][c] = fmaf(sv[rr][k], h[rr][c], po[k][c]);
#pragma unroll
  for (int k = 0; k < 4; ++k)
#pragma unroll
    for (int c = 0; c < 8; ++c) {
      po[k][c] += __shfl_xor(po[k][c], 16);
      po[k][c] += __shfl_xor(po[k][c], 32);
    }
  if ((t & 63) < 16) {
#pragma unroll
    for (int k = 0; k < 4; ++k)
#pragma unroll
      for (int c = 0; c < 8; ++c)
        atomicAdd(&outL[k][c0 + (c & 3) + (c >> 2) * 64], po[k][c]);
  }

  __syncthreads();
  // dense per-block partial writes (own contiguous region, full lines)
  for (int i = t; i < KC * HID; i += 256)
    pout[(size_t)bi * (KC * HID) + i] = ((const float*)outL)[i];
  if (t < 16) pss[bi * 16 + t] = ssL[t];
  if (t == 0) pden[bi] = denL;
}

// ---------------------------------------------------------------- K3b: reduce partials -> out_pool / ss_g / den_g
// NOTE: k_fused block bi covers graph bi&7, chunk bi>>3.
__global__ __launch_bounds__(256) void k_reduce(const float* __restrict__ pout,
                                                const float* __restrict__ pss,
                                                const float* __restrict__ pden,
                                                float* __restrict__ out_pool,
                                                float* __restrict__ ss_g,
                                                float* __restrict__ den_g) {
  const int t = threadIdx.x;
  if (blockIdx.x < 16) {
    const int b = blockIdx.x >> 1;
    const int i = ((blockIdx.x & 1) << 8) + t;  // 0..511
    float s = 0.f;
    for (int c = 0; c < CHUNKS; ++c)
      s += pout[(size_t)(c * 8 + b) * 512 + i];
    out_pool[b * 512 + i] = s;
  } else {
    if (t < 128) {
      const int b = t >> 4, k = t & 15;
      float s = 0.f;
      for (int c = 0; c < CHUNKS; ++c) s += pss[(c * 8 + b) * 16 + k];
      ss_g[b * 16 + k] = s;
    } else if (t < 136) {
      const int b = t - 128;
      float s = 0.f;
      for (int c = 0; c < CHUNKS; ++c) s += pden[c * 8 + b];
      den_g[b] = s;
    }
  }
}

// ---------------------------------------------------------------- K4: out_adj[b] = sum_n s[n] (x) t[n],  t[n] = sum_{e: dst=n} s[src]
__global__ __launch_bounds__(256) void k_adj2(const int* __restrict__ count,
                                              const int* __restrict__ rowptr,
                                              const int* __restrict__ csr,
                                              const float* __restrict__ s,
                                              float* __restrict__ adjraw) {
  __shared__ float accL[4][2][16];  // [wave][graph-within-block][k1*4+k2]
  const int t = threadIdx.x;
  if (t < 128) ((float*)accL)[t] = 0.f;
  __syncthreads();
  const int node = blockIdx.x * 256 + t;
  const int g0 = (blockIdx.x * 256) / BLK;
  if (node < NN) {
    const int gi = node / BLK - g0;  // 0 or 1
    const int deg = count[node];
    const int* sl = csr + rowptr[node];
    float t0 = 0.f, t1 = 0.f, t2 = 0.f, t3 = 0.f;
    for (int e = 0; e < deg; ++e) {
      float4 svv = *(const float4*)(s + (size_t)sl[e] * 4);
      t0 += svv.x; t1 += svv.y; t2 += svv.z; t3 += svv.w;
    }
    float4 sn = *(const float4*)(s + (size_t)node * 4);
    float* base = accL[t >> 6][gi];
#pragma unroll
    for (int i = 0; i < 16; ++i) {
      int idx = (i + t) & 15;  // stagger: 4-way instead of 64-way contention
      int hi = idx >> 2, lo = idx & 3;
      float a = (hi == 0) ? sn.x : (hi == 1) ? sn.y : (hi == 2) ? sn.z : sn.w;
      float b = (lo == 0) ? t0 : (lo == 1) ? t1 : (lo == 2) ? t2 : t3;
      atomicAdd(base + idx, a * b);
    }
  }
  __syncthreads();
  if (t < 32) {
    int gi = t >> 4, i = t & 15, gg = g0 + gi;
    if (gg < NB) {
      float v = accL[0][gi][i] + accL[1][gi][i] + accL[2][gi][i] + accL[3][gi][i];
      atomicAdd(&adjraw[gg * 16 + i], v);
    }
  }
}

// ---------------------------------------------------------------- K5a: per-graph tail
__global__ __launch_bounds__(128) void k_graph(
    const float* __restrict__ out_pool, const float* __restrict__ adjraw,
    const float* __restrict__ den_g, const float* __restrict__ ss_g,
    const float* __restrict__ Wrel3, const float* __restrict__ brel3,
    const float* __restrict__ Wroot3, const float* __restrict__ Wlin1,
    const float* __restrict__ blin1, const float* __restrict__ Wlin2,
    const float* __restrict__ blin2, float* __restrict__ d_out,
    float* __restrict__ scratch) {
  const int b = blockIdx.x, t = threadIdx.x;
  __shared__ float adjL[16], adjnL[16], dL[4];
  __shared__ float osL[128], msL[128], x2mL[128], x3L[128];
  if (t < 16) adjL[t] = adjraw[b * 16 + t];
  __syncthreads();
  if (t < 4) {
    float srow = 0.f;
#pragma unroll
    for (int l = 0; l < 4; ++l)
      if (l != t) srow += adjL[t * 4 + l];
    dL[t] = sqrtf(srow) + 1e-15f;
  }
  __syncthreads();
  if (t < 16) {
    int k1 = t >> 2, k2 = t & 3;
    float az = (k1 == k2) ? 0.f : adjL[t];
    float an = az / (dL[k2] * dL[k1]);
    adjnL[t] = an;
    d_out[400018 + b * 16 + t] = an;
  }
  __syncthreads();
  float o0 = out_pool[b * 512 + 0 * 128 + t];
  float o1 = out_pool[b * 512 + 1 * 128 + t];
  float o2 = out_pool[b * 512 + 2 * 128 + t];
  float o3 = out_pool[b * 512 + 3 * 128 + t];
  float m0 = adjnL[0] * o0 + adjnL[1] * o1 + adjnL[2] * o2 + adjnL[3] * o3;
  float m1 = adjnL[4] * o0 + adjnL[5] * o1 + adjnL[6] * o2 + adjnL[7] * o3;
  float m2 = adjnL[8] * o0 + adjnL[9] * o1 + adjnL[10] * o2 + adjnL[11] * o3;
  float m3 = adjnL[12] * o0 + adjnL[13] * o1 + adjnL[14] * o2 + adjnL[15] * o3;
  osL[t] = o0 + o1 + o2 + o3;
  msL[t] = m0 + m1 + m2 + m3;
  __syncthreads();
  float accc = brel3[t];
  for (int j = 0; j < 128; ++j)
    accc += 0.25f * (msL[j] * Wrel3[j * 128 + t] + osL[j] * Wroot3[j * 128 + t]);
  x2mL[t] = accc;
  __syncthreads();
  float a2 = blin1[t];
  for (int j = 0; j < 128; ++j) a2 += x2mL[j] * Wlin1[j * 128 + t];
  x3L[t] = fmaxf(a2, 0.f);
  __syncthreads();
  if (t < 2) {
    float lg = blin2[t];
    for (int j = 0; j < 128; ++j) lg += x3L[j] * Wlin2[j * 2 + t];
    scratch[b * 2 + t] = lg;
  }
  if (t == 0) {
    float tr = adjL[0] + adjL[5] + adjL[10] + adjL[15];
    scratch[16 + b] = tr / den_g[b];
    float n2 = 0.f;
    for (int i = 0; i < 16; ++i) { float v = ss_g[b * 16 + i]; n2 += v * v; }
    float nn = sqrtf(n2);
    float od = 0.f;
    for (int i = 0; i < 16; ++i) {
      float v = ss_g[b * 16 + i] / nn - (((i >> 2) == (i & 3)) ? 0.5f : 0.f);
      od += v * v;
    }
    scratch[24 + b] = sqrtf(od);
  }
}

// ---------------------------------------------------------------- K5b: losses + log_softmax
__global__ void k_final(const float* __restrict__ scratch, float* __restrict__ d_out) {
  if (threadIdx.x == 0 && blockIdx.x == 0) {
    float mc = 0.f, oo = 0.f;
    for (int b = 0; b < NB; ++b) { mc += scratch[16 + b]; oo += scratch[24 + b]; }
    d_out[16] = -(mc / (float)NB);
    d_out[17] = oo / (float)NB;
    for (int b = 0; b < NB; ++b) {
      float l0 = scratch[2 * b], l1 = scratch[2 * b + 1];
      float m = fmaxf(l0, l1);
      float lse = m + logf(expf(l0 - m) + expf(l1 - m));
      d_out[2 * b] = l0 - lse;
      d_out[2 * b + 1] = l1 - lse;
    }
  }
}

// ---------------------------------------------------------------- launch
extern "C" void kernel_launch(void* const* d_in, const int* in_sizes, int n_in,
                              void* d_out, int out_size, void* d_ws, size_t ws_size,
                              hipStream_t stream) {
  (void)in_sizes; (void)n_in; (void)out_size; (void)ws_size;
  const float* x      = (const float*)d_in[0];
  const int*   ei     = (const int*)d_in[1];
  const float* Wroot1 = (const float*)d_in[3];
  const float* Wrel1  = (const float*)d_in[4];
  const float* brel1  = (const float*)d_in[5];
  const float* Wpool  = (const float*)d_in[6];
  const float* bpool  = (const float*)d_in[7];
  const float* Wrel3  = (const float*)d_in[8];
  const float* brel3  = (const float*)d_in[9];
  const float* Wroot3 = (const float*)d_in[10];
  const float* Wlin1  = (const float*)d_in[11];
  const float* blin1  = (const float*)d_in[12];
  const float* Wlin2  = (const float*)d_in[13];
  const float* blin2  = (const float*)d_in[14];
  float* out = (float*)d_out;

  char* ws = (char*)d_ws;
  float*  out_pool = (float*)(ws + 0);          //  16384 B
  float*  ss_g     = (float*)(ws + 16384);      //    512 B
  float*  adjraw   = (float*)(ws + 16896);      //    512 B (memset)
  float*  den_g    = (float*)(ws + 17408);      //     32 B
  float*  scratch  = (float*)(ws + 17440);      //    128 B (memset)
  int*    sbcnt    = (int*)(ws + 17568);        //   1568 B (memset)
  int*    sbbase   = (int*)(ws + 19136);        //   1600 B
  int*    count    = (int*)(ws + 20736);        // 400000 B
  int*    rowptr   = (int*)(ws + 420736);       // 400016 B
  ushort* Wt       = (ushort*)(ws + 820752);    //  65536 B [128][256]
  int*    csr      = (int*)(ws + 886288);       // 6400000 B [E]
  ushort* xb       = (ushort*)(ws + 7286288);   // 25600000 B [N][128] bf16
  uint*   gbuf     = (uint*)(ws + 32886288);    // 392 x 5120 x 4 = 8028160 B
  float*  pout     = (float*)(ws + 58486288);   // 1568 x 512 x 4 = 3211264 B
  float*  pss      = (float*)(ws + 61697552);   // 1568 x 16 x 4 = 100352 B
  float*  pden     = (float*)(ws + 61797904);   // 1568 x 4 = 6272 B

  hipMemsetAsync(ws, 0, 19136, stream);
  k_prep_x<<<12500, 256, 0, stream>>>((const float4*)x, xb);
  k_prep_w<<<128, 256, 0, stream>>>(Wrel1, Wroot1, Wt);
  k_bucket2<<<196, 256, 0, stream>>>(ei, sbcnt, gbuf);
  k_scan392<<<1, 512, 0, stream>>>(sbcnt, sbbase);
  k_csr_tile<<<NBIN, 256, 0, stream>>>(gbuf, sbcnt, sbbase, rowptr, count, csr);
  k_fused<<<NB * CHUNKS, 256, 0, stream>>>(xb, Wt, brel1, Wpool, bpool, count, rowptr,
                                           csr, out + 18, pout, pss, pden);
  k_reduce<<<17, 256, 0, stream>>>(pout, pss, pden, out_pool, ss_g, den_g);
  k_adj2<<<(NN + 255) / 256, 256, 0, stream>>>(count, rowptr, csr, out + 18, adjraw);
  k_graph<<<NB, 128, 0, stream>>>(out_pool, adjraw, den_g, ss_g, Wrel3, brel3, Wroot3,
                                  Wlin1, blin1, Wlin2, blin2, out, scratch);
  k_final<<<1, 64, 0, stream>>>(scratch, out);
}

// Round 13
// 224.717 us; speedup vs baseline: 1.3379x; 1.3379x over previous
//
#include <hip/hip_runtime.h>

// Problem constants (fixed by the reference)
#define NN     100000      // nodes
#define EE     1600000     // edges
#define NB     8           // graphs
#define BLK    12500       // nodes per graph
#define HID    128
#define KC     4
#define CHUNKS 196         // ceil(12500/64)
#define NTILE  49          // dst-ranges of 256 nodes per graph
#define NBIN   392         // 8 graphs x 49 tiles
#define GCAPS  5120        // per-bin capacity (mean 4081, sigma ~64)

typedef __attribute__((ext_vector_type(8))) short bf16x8;
typedef __attribute__((ext_vector_type(4))) float f32x4;

__device__ __forceinline__ ushort f2bf(float f) {
  uint u = __float_as_uint(f);
  return (ushort)((u + 0x7FFFu + ((u >> 16) & 1u)) >> 16);  // RNE
}
__device__ __forceinline__ float bf2f(ushort h) {
  return __uint_as_float(((uint)h) << 16);
}

// ---------------------------------------------------------------- K0a: x -> bf16
__global__ __launch_bounds__(256) void k_prep_x(const float4* __restrict__ x4,
                                                ushort* __restrict__ xb) {
  int i = blockIdx.x * 256 + threadIdx.x;  // 3.2M float4s exactly
  float4 v = x4[i];
  ushort4 r;
  r.x = f2bf(v.x); r.y = f2bf(v.y); r.z = f2bf(v.z); r.w = f2bf(v.w);
  *(ushort4*)(xb + (size_t)i * 4) = r;
}

// ---------------------------------------------------------------- K0b: Wt[col][k], k<128 = Wrel1, k>=128 = Wroot1
__global__ __launch_bounds__(256) void k_prep_w(const float* __restrict__ Wrel1,
                                                const float* __restrict__ Wroot1,
                                                ushort* __restrict__ Wt) {
  int col = blockIdx.x, k = threadIdx.x;
  float v = (k < 128) ? Wrel1[k * 128 + col] : Wroot1[(k - 128) * 128 + col];
  Wt[col * 256 + k] = f2bf(v);
}

// ---------------------------------------------------------------- K1a: edges -> 392 (graph, dst-range) sub-buckets
__global__ __launch_bounds__(256) void k_bucket2(const int* __restrict__ ei,
                                                 int* __restrict__ sbcnt,
                                                 uint* __restrict__ gbuf) {
  __shared__ uint stage[8192];
  __shared__ int cnt[NBIN], start[NBIN + 1], rbase[NBIN];
  __shared__ int gtot[8], gb[8];
  const int t = threadIdx.x;
  for (int b = t; b < NBIN; b += 256) cnt[b] = 0;
  __syncthreads();
  const int e0 = blockIdx.x * 8192;
  uint pk[32]; int br[32];
#pragma unroll
  for (int i = 0; i < 32; ++i) {
    int e = e0 + i * 256 + t;
    bool val = (e < EE);
    int src = 0, dst = 0;
    if (val) {
      src = __builtin_nontemporal_load(ei + e);
      dst = __builtin_nontemporal_load(ei + EE + e);
    }
    int g = dst / BLK;
    int dl = dst - g * BLK;
    int sl = src - g * BLK;
    int bin = g * NTILE + (dl >> 8);
    pk[i] = ((uint)sl << 16) | (uint)dl;
    br[i] = val ? ((bin << 14) | atomicAdd(&cnt[bin], 1)) : -1;
  }
  __syncthreads();
  if (t < 8) {
    int s = 0;
    for (int k = 0; k < NTILE; ++k) s += cnt[t * NTILE + k];
    gtot[t] = s;
  }
  __syncthreads();
  if (t == 0) {
    int s = 0;
    for (int g = 0; g < 8; ++g) { gb[g] = s; s += gtot[g]; }
    start[NBIN] = s;
  }
  __syncthreads();
  if (t < 8) {
    int run = gb[t];
    for (int k = 0; k < NTILE; ++k) { start[t * NTILE + k] = run; run += cnt[t * NTILE + k]; }
  }
  __syncthreads();
  for (int b = t; b < NBIN; b += 256) rbase[b] = atomicAdd(&sbcnt[b], cnt[b]);
#pragma unroll
  for (int i = 0; i < 32; ++i) {
    if (br[i] >= 0) {
      int bin = br[i] >> 14, rank = br[i] & 16383;
      stage[start[bin] + rank] = pk[i];
    }
  }
  __syncthreads();
  const int total = start[NBIN];
  for (int j = t; j < total; j += 256) {
    int lo = 0, hi = NBIN - 1;  // largest bin with start[bin] <= j
    while (lo < hi) { int mid = (lo + hi + 1) >> 1; if (j >= start[mid]) lo = mid; else hi = mid - 1; }
    gbuf[(size_t)lo * GCAPS + rbase[lo] + (j - start[lo])] = stage[j];
  }
}

// ---------------------------------------------------------------- K1b: exclusive scan of bin sizes
__global__ __launch_bounds__(512) void k_scan392(const int* __restrict__ sbcnt,
                                                 int* __restrict__ sbbase) {
  __shared__ int sd[512];
  const int t = threadIdx.x;
  int v = (t < NBIN) ? sbcnt[t] : 0;
  sd[t] = v;
  __syncthreads();
  for (int s = 1; s < 512; s <<= 1) {
    int x = (t >= s) ? sd[t - s] : 0;
    __syncthreads();
    sd[t] += x;
    __syncthreads();
  }
  if (t < NBIN) sbbase[t] = sd[t] - v;
}

// ---------------------------------------------------------------- K1c: per-bin LDS counting sort -> dense CSR segment + rowptr + count
__global__ __launch_bounds__(256) void k_csr_tile(const uint* __restrict__ gbuf,
                                                  const int* __restrict__ sbcnt,
                                                  const int* __restrict__ sbbase,
                                                  int* __restrict__ rowptr,
                                                  int* __restrict__ count,
                                                  int* __restrict__ csr) {
  const int g = blockIdx.x & 7;     // XCD-local per graph
  const int tile = blockIdx.x >> 3; // 0..48
  const int bin = g * NTILE + tile;
  const int m = sbcnt[bin];
  const int base = sbbase[bin];
  const int n0t = tile * 256;
  const int nt = min(256, BLK - n0t);
  __shared__ uint ent[GCAPS];
  __shared__ ushort srt[GCAPS];
  __shared__ int cnt[256], scn[256], cur[256];
  const int t = threadIdx.x;
  cnt[t] = 0;
  __syncthreads();
  const uint* buf = gbuf + (size_t)bin * GCAPS;
  for (int i = t; i < m; i += 256) {
    uint pk = buf[i];
    ent[i] = pk;
    atomicAdd(&cnt[(int)(pk & 0xFFFFu) - n0t], 1);
  }
  __syncthreads();
  int v = cnt[t];
  scn[t] = v;
  __syncthreads();
  for (int s = 1; s < 256; s <<= 1) {
    int x = (t >= s) ? scn[t - s] : 0;
    __syncthreads();
    scn[t] += x;
    __syncthreads();
  }
  int excl = scn[t] - v;
  cur[t] = excl;
  if (t < nt) {
    rowptr[g * BLK + n0t + t] = base + excl;
    count[g * BLK + n0t + t] = v;
  }
  __syncthreads();
  for (int i = t; i < m; i += 256) {
    uint pk = ent[i];
    int p = atomicAdd(&cur[(int)(pk & 0xFFFFu) - n0t], 1);
    srt[p] = (ushort)(pk >> 16);
  }
  __syncthreads();
  const int nb = g * BLK;
  for (int i = t; i < m; i += 256)
    csr[base + i] = nb + (int)srt[i];  // dense coalesced
}

// ---------------------------------------------------------------- K2: agg[n] = sum_{e: dst=n} x[src]  (bf16, fp32 accum)
// R13: (a) 4-way edge unroll with 4 independent accumulator sets -> 4 row
// loads in flight per chain (was 1: runtime-bounded loop serialized at full
// L2 latency). (b) volatile read-PRIME of the aggb destination line before
// the store: gfx950 L2 has no write-allocate, but stores to PRESENT lines
// stay in L2 -> k_fused (mapped to the same XCD, bi&7=graph) reads hit L2.
__global__ __launch_bounds__(256) void k_agg2(const ushort* __restrict__ xb,
                                              const int* __restrict__ count,
                                              const int* __restrict__ rowptr,
                                              const int* __restrict__ csr,
                                              ushort* __restrict__ aggb) {
  const int xg = blockIdx.x & 7;
  const int j = blockIdx.x >> 3;
  const int half = threadIdx.x >> 5;  // 8 half-waves = 8 nodes per block
  const int lane = threadIdx.x & 31;
  const int ln = j * 8 + half;
  if (ln >= BLK) return;
  const int node = xg * BLK + ln;
  const int deg = count[node];
  const int* sl = csr + rowptr[node];
  int idx0 = (lane < deg) ? sl[lane] : 0;
  int idx1 = (32 + lane < deg) ? sl[32 + lane] : 0;

#define GETIDX(e) ((e) < 32 ? __shfl(idx0, (e), 32) \
                            : ((e) < 64 ? __shfl(idx1, (e) - 32, 32) : sl[(e)]))

  float A0 = 0.f, A1 = 0.f, A2 = 0.f, A3 = 0.f;
  float B0 = 0.f, B1 = 0.f, B2 = 0.f, B3 = 0.f;
  float C0 = 0.f, C1 = 0.f, C2 = 0.f, C3 = 0.f;
  float D0 = 0.f, D1 = 0.f, D2 = 0.f, D3 = 0.f;
  int e = 0;
  for (; e + 4 <= deg; e += 4) {
    int s0 = GETIDX(e + 0);
    int s1 = GETIDX(e + 1);
    int s2 = GETIDX(e + 2);
    int s3 = GETIDX(e + 3);
    ushort4 v0 = *(const ushort4*)(xb + (size_t)s0 * HID + lane * 4);
    ushort4 v1 = *(const ushort4*)(xb + (size_t)s1 * HID + lane * 4);
    ushort4 v2 = *(const ushort4*)(xb + (size_t)s2 * HID + lane * 4);
    ushort4 v3 = *(const ushort4*)(xb + (size_t)s3 * HID + lane * 4);
    A0 += bf2f(v0.x); A1 += bf2f(v0.y); A2 += bf2f(v0.z); A3 += bf2f(v0.w);
    B0 += bf2f(v1.x); B1 += bf2f(v1.y); B2 += bf2f(v1.z); B3 += bf2f(v1.w);
    C0 += bf2f(v2.x); C1 += bf2f(v2.y); C2 += bf2f(v2.z); C3 += bf2f(v2.w);
    D0 += bf2f(v3.x); D1 += bf2f(v3.y); D2 += bf2f(v3.z); D3 += bf2f(v3.w);
  }
  for (; e < deg; ++e) {
    int s0 = GETIDX(e);
    ushort4 v0 = *(const ushort4*)(xb + (size_t)s0 * HID + lane * 4);
    A0 += bf2f(v0.x); A1 += bf2f(v0.y); A2 += bf2f(v0.z); A3 += bf2f(v0.w);
  }
#undef GETIDX

  // prime destination line into L2 (volatile: not DCE'd; same-address store
  // below is ordered after)
  ushort* dstp = aggb + (size_t)node * HID + lane * 4;
  {
    volatile const uint* pr = (volatile const uint*)dstp;
    uint d0 = pr[0];
    uint d1 = pr[1];
    (void)d0; (void)d1;
  }
  ushort4 r;
  r.x = f2bf(A0 + B0 + C0 + D0);
  r.y = f2bf(A1 + B1 + C1 + D1);
  r.z = f2bf(A2 + B2 + C2 + D2);
  r.w = f2bf(A3 + B3 + C3 + D3);
  *(ushort4*)dstp = r;
}

// ---------------------------------------------------------------- K3: MFMA GEMM + softmax + pooled reductions (R8 body)
// Graph mapping bi&7 aligns each block's XCD with k_agg2's, so A-reads hit
// the aggb lines that k_agg2's read-prime left resident in that XCD's L2.
__global__ __launch_bounds__(256) void k_fused(
    const ushort* __restrict__ aggb, const ushort* __restrict__ xb,
    const ushort* __restrict__ Wt, const float* __restrict__ brel1,
    const float* __restrict__ Wpool, const float* __restrict__ bpool,
    const int* __restrict__ count, float* __restrict__ s_out,
    float* __restrict__ out_pool, float* __restrict__ ss_g,
    float* __restrict__ den_g) {
  __shared__ float hL[64][132];     // h tile (pad 128->132)
  __shared__ float outL[KC][HID];
  __shared__ float ssL[16];
  __shared__ float denL;

  const int t = threadIdx.x;
  const int bi = blockIdx.x;
  const int bG = bi & 7;            // graph = XCD (round-robin)
  const int chunk = bi >> 3;
  const int node0 = bG * BLK + chunk * 64;
  int nrows = BLK - chunk * 64;
  if (nrows > 64) nrows = 64;

  for (int i = t; i < KC * HID; i += 256) ((float*)outL)[i] = 0.f;
  if (t < 16) ssL[t] = 0.f;
  if (t == 0) denL = 0.f;

  const int w = t >> 6;     // wave: cols 32w..32w+31
  const int l = t & 63;
  const int m16 = l & 15;
  const int gq = l >> 4;

  // ---- B fragments: registers, loaded once (L2-hot, 64 KB shared) ----
  bf16x8 Breg[8][2];
#pragma unroll
  for (int kt = 0; kt < 8; ++kt)
#pragma unroll
    for (int fc = 0; fc < 2; ++fc)
      Breg[kt][fc] =
          *(const bf16x8*)(Wt + (size_t)(32 * w + 16 * fc + m16) * 256 + kt * 32 + 8 * gq);

  // ---- A row pointers (per fragment row, tail-clamped) ----
  const ushort* Arow_ag[4];
  const ushort* Arow_x[4];
#pragma unroll
  for (int fr = 0; fr < 4; ++fr) {
    int r = 16 * fr + m16;
    if (r >= nrows) r = nrows - 1;
    Arow_ag[fr] = aggb + (size_t)(node0 + r) * HID + 8 * gq;
    Arow_x[fr]  = xb   + (size_t)(node0 + r) * HID + 8 * gq;
  }

  f32x4 acc[4][2];
#pragma unroll
  for (int fr = 0; fr < 4; ++fr)
#pragma unroll
    for (int fc = 0; fc < 2; ++fc) acc[fr][fc] = (f32x4){0.f, 0.f, 0.f, 0.f};

#pragma unroll
  for (int kt = 0; kt < 8; ++kt) {
    const int off = (kt & 3) * 32;
    bf16x8 af[4];
#pragma unroll
    for (int fr = 0; fr < 4; ++fr)
      af[fr] = *(const bf16x8*)((kt < 4 ? Arow_ag[fr] : Arow_x[fr]) + off);
#pragma unroll
    for (int fr = 0; fr < 4; ++fr)
#pragma unroll
      for (int fc = 0; fc < 2; ++fc)
        acc[fr][fc] = __builtin_amdgcn_mfma_f32_16x16x32_bf16(af[fr], Breg[kt][fc],
                                                              acc[fr][fc], 0, 0, 0);
  }

  // bias + relu -> hL  (D layout: row = 4*(l>>4)+reg, col = l&15  [m89])
  const float bc0 = brel1[32 * w + m16];
  const float bc1 = brel1[32 * w + 16 + m16];
#pragma unroll
  for (int fr = 0; fr < 4; ++fr)
#pragma unroll
    for (int fc = 0; fc < 2; ++fc)
#pragma unroll
      for (int r = 0; r < 4; ++r)
        hL[16 * fr + 4 * gq + r][32 * w + 16 * fc + m16] =
            fmaxf(acc[fr][fc][r] + (fc ? bc1 : bc0), 0.f);
  __syncthreads();

  // ---- epilogue (16-lane groups own 4 rows each) ----
  const int g4 = t >> 4;
  const int c0 = (t & 15) << 2;
  const int li = t & 15;

  float h[4][8];
#pragma unroll
  for (int r = 0; r < 4; ++r) {
    float4 v0 = *(const float4*)&hL[g4 * 4 + r][c0];
    float4 v1 = *(const float4*)&hL[g4 * 4 + r][c0 + 64];
    h[r][0] = v0.x; h[r][1] = v0.y; h[r][2] = v0.z; h[r][3] = v0.w;
    h[r][4] = v1.x; h[r][5] = v1.y; h[r][6] = v1.z; h[r][7] = v1.w;
  }

  // pooling head: p = h @ Wpool
  float wp[8][4];
#pragma unroll
  for (int j = 0; j < 8; ++j) {
    int col = c0 + (j & 3) + (j >> 2) * 64;
    float4 v = *(const float4*)(Wpool + col * 4);
    wp[j][0] = v.x; wp[j][1] = v.y; wp[j][2] = v.z; wp[j][3] = v.w;
  }
  float pp[4][4];
#pragma unroll
  for (int r = 0; r < 4; ++r)
#pragma unroll
    for (int k = 0; k < 4; ++k) pp[r][k] = 0.f;
#pragma unroll
  for (int r = 0; r < 4; ++r)
#pragma unroll
    for (int j = 0; j < 8; ++j)
#pragma unroll
      for (int k = 0; k < 4; ++k) pp[r][k] = fmaf(h[r][j], wp[j][k], pp[r][k]);
#pragma unroll
  for (int m = 1; m <= 8; m <<= 1)
#pragma unroll
    for (int r = 0; r < 4; ++r)
#pragma unroll
      for (int k = 0; k < 4; ++k) pp[r][k] += __shfl_xor(pp[r][k], m);

  float4 bp4 = *(const float4*)bpool;
  float bp[4] = {bp4.x, bp4.y, bp4.z, bp4.w};
  float sv[4][4];
#pragma unroll
  for (int r = 0; r < 4; ++r) {
    float p[4];
#pragma unroll
    for (int k = 0; k < 4; ++k) p[k] = pp[r][k] + bp[k];
    float mx = fmaxf(fmaxf(p[0], p[1]), fmaxf(p[2], p[3]));
    float e0 = expf(p[0] - mx), e1 = expf(p[1] - mx), e2 = expf(p[2] - mx), e3 = expf(p[3] - mx);
    float inv = 1.f / (e0 + e1 + e2 + e3);
    float valid = (g4 * 4 + r < nrows) ? 1.f : 0.f;
    sv[r][0] = e0 * inv * valid; sv[r][1] = e1 * inv * valid;
    sv[r][2] = e2 * inv * valid; sv[r][3] = e3 * inv * valid;
  }

  // write s
  {
    int rW = li >> 2, kW = li & 3;
    if (g4 * 4 + rW < nrows) {
      int node = node0 + g4 * 4 + rW;
      float val = 0.f;
#pragma unroll
      for (int rr = 0; rr < 4; ++rr)
#pragma unroll
        for (int kk = 0; kk < 4; ++kk)
          if (li == rr * 4 + kk) val = sv[rr][kk];
      s_out[node * 4 + kW] = val;
    }
  }

  // ss[b][k1][k2]
  {
    int k1 = li >> 2, k2 = li & 3;
    float a1[4], a2[4];
#pragma unroll
    for (int rr = 0; rr < 4; ++rr) {
      float v1 = 0.f, v2 = 0.f;
#pragma unroll
      for (int kk = 0; kk < 4; ++kk) {
        if (k1 == kk) v1 = sv[rr][kk];
        if (k2 == kk) v2 = sv[rr][kk];
      }
      a1[rr] = v1; a2[rr] = v2;
    }
    float ssv = a1[0] * a2[0] + a1[1] * a2[1] + a1[2] * a2[2] + a1[3] * a2[3];
    atomicAdd(&ssL[li], ssv);
  }

  // den += deg * ||s||^2
  if (li == 0) {
    float dent = 0.f;
#pragma unroll
    for (int rr = 0; rr < 4; ++rr) {
      int rowg = g4 * 4 + rr;
      if (rowg < nrows) {
        float dg = (float)count[node0 + rowg];
        dent += dg * (sv[rr][0] * sv[rr][0] + sv[rr][1] * sv[rr][1] +
                      sv[rr][2] * sv[rr][2] + sv[rr][3] * sv[rr][3]);
      }
    }
    atomicAdd(&denL, dent);
  }

  // out[k][c] += s[r][k]*h[r][c]
  float po[4][8];
#pragma unroll
  for (int k = 0; k < 4; ++k)
#pragma unroll
    for (int c = 0; c < 8; ++c) po[k][c] = 0.f;
#pragma unroll
  for (int k = 0; k < 4; ++k)
#pragma unroll
    for (int rr = 0; rr < 4; ++rr)
#pragma unroll
      for (int c = 0; c < 8; ++c) po[k][c] = fmaf(sv[rr][k], h[rr][c], po[k][c]);
#pragma unroll
  for (int k = 0; k < 4; ++k)
#pragma unroll
    for (int c = 0; c < 8; ++c) {
      po[k][c] += __shfl_xor(po[k][c], 16);
      po[k][c] += __shfl_xor(po[k][c], 32);
    }
  if ((t & 63) < 16) {
#pragma unroll
    for (int k = 0; k < 4; ++k)
#pragma unroll
      for (int c = 0; c < 8; ++c)
        atomicAdd(&outL[k][c0 + (c & 3) + (c >> 2) * 64], po[k][c]);
  }

  __syncthreads();
  for (int i = t; i < KC * HID; i += 256)
    atomicAdd(&out_pool[bG * KC * HID + i], ((const float*)outL)[i]);
  if (t < 16) atomicAdd(&ss_g[bG * 16 + t], ssL[t]);
  if (t == 0) atomicAdd(&den_g[bG], denL);
}

// ---------------------------------------------------------------- K4: out_adj[b] = sum_n s[n] (x) t[n],  t[n] = sum_{e: dst=n} s[src]
// R13: 4-way edge unroll (4 independent s-row loads in flight per node).
__global__ __launch_bounds__(256) void k_adj2(const int* __restrict__ count,
                                              const int* __restrict__ rowptr,
                                              const int* __restrict__ csr,
                                              const float* __restrict__ s,
                                              float* __restrict__ adjraw) {
  __shared__ float accL[4][2][16];  // [wave][graph-within-block][k1*4+k2]
  const int t = threadIdx.x;
  if (t < 128) ((float*)accL)[t] = 0.f;
  __syncthreads();
  const int node = blockIdx.x * 256 + t;
  const int g0 = (blockIdx.x * 256) / BLK;
  if (node < NN) {
    const int gi = node / BLK - g0;  // 0 or 1
    const int deg = count[node];
    const int* sl = csr + rowptr[node];
    float A0 = 0.f, A1 = 0.f, A2 = 0.f, A3 = 0.f;
    float B0 = 0.f, B1 = 0.f, B2 = 0.f, B3 = 0.f;
    float C0 = 0.f, C1 = 0.f, C2 = 0.f, C3 = 0.f;
    float D0 = 0.f, D1 = 0.f, D2 = 0.f, D3 = 0.f;
    int e = 0;
    for (; e + 4 <= deg; e += 4) {
      int s0 = sl[e + 0], s1 = sl[e + 1], s2 = sl[e + 2], s3 = sl[e + 3];
      float4 v0 = *(const float4*)(s + (size_t)s0 * 4);
      float4 v1 = *(const float4*)(s + (size_t)s1 * 4);
      float4 v2 = *(const float4*)(s + (size_t)s2 * 4);
      float4 v3 = *(const float4*)(s + (size_t)s3 * 4);
      A0 += v0.x; A1 += v0.y; A2 += v0.z; A3 += v0.w;
      B0 += v1.x; B1 += v1.y; B2 += v1.z; B3 += v1.w;
      C0 += v2.x; C1 += v2.y; C2 += v2.z; C3 += v2.w;
      D0 += v3.x; D1 += v3.y; D2 += v3.z; D3 += v3.w;
    }
    for (; e < deg; ++e) {
      float4 v0 = *(const float4*)(s + (size_t)sl[e] * 4);
      A0 += v0.x; A1 += v0.y; A2 += v0.z; A3 += v0.w;
    }
    float t0 = A0 + B0 + C0 + D0;
    float t1 = A1 + B1 + C1 + D1;
    float t2 = A2 + B2 + C2 + D2;
    float t3 = A3 + B3 + C3 + D3;
    float4 sn = *(const float4*)(s + (size_t)node * 4);
    float* base = accL[t >> 6][gi];
#pragma unroll
    for (int i = 0; i < 16; ++i) {
      int idx = (i + t) & 15;  // stagger: 4-way instead of 64-way contention
      int hi = idx >> 2, lo = idx & 3;
      float a = (hi == 0) ? sn.x : (hi == 1) ? sn.y : (hi == 2) ? sn.z : sn.w;
      float b = (lo == 0) ? t0 : (lo == 1) ? t1 : (lo == 2) ? t2 : t3;
      atomicAdd(base + idx, a * b);
    }
  }
  __syncthreads();
  if (t < 32) {
    int gi = t >> 4, i = t & 15, gg = g0 + gi;
    if (gg < NB) {
      float v = accL[0][gi][i] + accL[1][gi][i] + accL[2][gi][i] + accL[3][gi][i];
      atomicAdd(&adjraw[gg * 16 + i], v);
    }
  }
}

// ---------------------------------------------------------------- K5a: per-graph tail
__global__ __launch_bounds__(128) void k_graph(
    const float* __restrict__ out_pool, const float* __restrict__ adjraw,
    const float* __restrict__ den_g, const float* __restrict__ ss_g,
    const float* __restrict__ Wrel3, const float* __restrict__ brel3,
    const float* __restrict__ Wroot3, const float* __restrict__ Wlin1,
    const float* __restrict__ blin1, const float* __restrict__ Wlin2,
    const float* __restrict__ blin2, float* __restrict__ d_out,
    float* __restrict__ scratch) {
  const int b = blockIdx.x, t = threadIdx.x;
  __shared__ float adjL[16], adjnL[16], dL[4];
  __shared__ float osL[128], msL[128], x2mL[128], x3L[128];
  if (t < 16) adjL[t] = adjraw[b * 16 + t];
  __syncthreads();
  if (t < 4) {
    float srow = 0.f;
#pragma unroll
    for (int l = 0; l < 4; ++l)
      if (l != t) srow += adjL[t * 4 + l];
    dL[t] = sqrtf(srow) + 1e-15f;
  }
  __syncthreads();
  if (t < 16) {
    int k1 = t >> 2, k2 = t & 3;
    float az = (k1 == k2) ? 0.f : adjL[t];
    float an = az / (dL[k2] * dL[k1]);
    adjnL[t] = an;
    d_out[400018 + b * 16 + t] = an;
  }
  __syncthreads();
  float o0 = out_pool[b * 512 + 0 * 128 + t];
  float o1 = out_pool[b * 512 + 1 * 128 + t];
  float o2 = out_pool[b * 512 + 2 * 128 + t];
  float o3 = out_pool[b * 512 + 3 * 128 + t];
  float m0 = adjnL[0] * o0 + adjnL[1] * o1 + adjnL[2] * o2 + adjnL[3] * o3;
  float m1 = adjnL[4] * o0 + adjnL[5] * o1 + adjnL[6] * o2 + adjnL[7] * o3;
  float m2 = adjnL[8] * o0 + adjnL[9] * o1 + adjnL[10] * o2 + adjnL[11] * o3;
  float m3 = adjnL[12] * o0 + adjnL[13] * o1 + adjnL[14] * o2 + adjnL[15] * o3;
  osL[t] = o0 + o1 + o2 + o3;
  msL[t] = m0 + m1 + m2 + m3;
  __syncthreads();
  float accc = brel3[t];
  for (int j = 0; j < 128; ++j)
    accc += 0.25f * (msL[j] * Wrel3[j * 128 + t] + osL[j] * Wroot3[j * 128 + t]);
  x2mL[t] = accc;
  __syncthreads();
  float a2 = blin1[t];
  for (int j = 0; j < 128; ++j) a2 += x2mL[j] * Wlin1[j * 128 + t];
  x3L[t] = fmaxf(a2, 0.f);
  __syncthreads();
  if (t < 2) {
    float lg = blin2[t];
    for (int j = 0; j < 128; ++j) lg += x3L[j] * Wlin2[j * 2 + t];
    scratch[b * 2 + t] = lg;
  }
  if (t == 0) {
    float tr = adjL[0] + adjL[5] + adjL[10] + adjL[15];
    scratch[16 + b] = tr / den_g[b];
    float n2 = 0.f;
    for (int i = 0; i < 16; ++i) { float v = ss_g[b * 16 + i]; n2 += v * v; }
    float nn = sqrtf(n2);
    float od = 0.f;
    for (int i = 0; i < 16; ++i) {
      float v = ss_g[b * 16 + i] / nn - (((i >> 2) == (i & 3)) ? 0.5f : 0.f);
      od += v * v;
    }
    scratch[24 + b] = sqrtf(od);
  }
}

// ---------------------------------------------------------------- K5b: losses + log_softmax
__global__ void k_final(const float* __restrict__ scratch, float* __restrict__ d_out) {
  if (threadIdx.x == 0 && blockIdx.x == 0) {
    float mc = 0.f, oo = 0.f;
    for (int b = 0; b < NB; ++b) { mc += scratch[16 + b]; oo += scratch[24 + b]; }
    d_out[16] = -(mc / (float)NB);
    d_out[17] = oo / (float)NB;
    for (int b = 0; b < NB; ++b) {
      float l0 = scratch[2 * b], l1 = scratch[2 * b + 1];
      float m = fmaxf(l0, l1);
      float lse = m + logf(expf(l0 - m) + expf(l1 - m));
      d_out[2 * b] = l0 - lse;
      d_out[2 * b + 1] = l1 - lse;
    }
  }
}

// ---------------------------------------------------------------- launch
extern "C" void kernel_launch(void* const* d_in, const int* in_sizes, int n_in,
                              void* d_out, int out_size, void* d_ws, size_t ws_size,
                              hipStream_t stream) {
  (void)in_sizes; (void)n_in; (void)out_size; (void)ws_size;
  const float* x      = (const float*)d_in[0];
  const int*   ei     = (const int*)d_in[1];
  const float* Wroot1 = (const float*)d_in[3];
  const float* Wrel1  = (const float*)d_in[4];
  const float* brel1  = (const float*)d_in[5];
  const float* Wpool  = (const float*)d_in[6];
  const float* bpool  = (const float*)d_in[7];
  const float* Wrel3  = (const float*)d_in[8];
  const float* brel3  = (const float*)d_in[9];
  const float* Wroot3 = (const float*)d_in[10];
  const float* Wlin1  = (const float*)d_in[11];
  const float* blin1  = (const float*)d_in[12];
  const float* Wlin2  = (const float*)d_in[13];
  const float* blin2  = (const float*)d_in[14];
  float* out = (float*)d_out;

  char* ws = (char*)d_ws;
  float*  out_pool = (float*)(ws + 0);          //  16384 B (memset)
  float*  ss_g     = (float*)(ws + 16384);      //    512 B (memset)
  float*  adjraw   = (float*)(ws + 16896);      //    512 B (memset)
  float*  den_g    = (float*)(ws + 17408);      //     32 B (memset)
  float*  scratch  = (float*)(ws + 17440);      //    128 B (memset)
  int*    sbcnt    = (int*)(ws + 17568);        //   1568 B (memset)
  int*    sbbase   = (int*)(ws + 19136);        //   1600 B
  int*    count    = (int*)(ws + 20736);        // 400000 B
  int*    rowptr   = (int*)(ws + 420736);       // 400016 B
  ushort* Wt       = (ushort*)(ws + 820752);    //  65536 B [128][256]
  int*    csr      = (int*)(ws + 886288);       // 6400000 B [E]
  ushort* xb       = (ushort*)(ws + 7286288);   // 25600000 B [N][128] bf16
  ushort* aggb     = (ushort*)(ws + 32886288);  // 25600000 B [N][128] bf16
  // gbuf (392 x 5120 x 4 = 8.03 MB) aliases nothing here: placed after aggb
  uint*   gbuf     = (uint*)(ws + 58486288);    // 8028160 B

  hipMemsetAsync(ws, 0, 19136, stream);
  k_prep_x<<<12500, 256, 0, stream>>>((const float4*)x, xb);
  k_prep_w<<<128, 256, 0, stream>>>(Wrel1, Wroot1, Wt);
  k_bucket2<<<196, 256, 0, stream>>>(ei, sbcnt, gbuf);
  k_scan392<<<1, 512, 0, stream>>>(sbcnt, sbbase);
  k_csr_tile<<<NBIN, 256, 0, stream>>>(gbuf, sbcnt, sbbase, rowptr, count, csr);
  k_agg2<<<8 * ((BLK + 7) / 8), 256, 0, stream>>>(xb, count, rowptr, csr, aggb);
  k_fused<<<NB * CHUNKS, 256, 0, stream>>>(aggb, xb, Wt, brel1, Wpool, bpool, count,
                                           out + 18, out_pool, ss_g, den_g);
  k_adj2<<<(NN + 255) / 256, 256, 0, stream>>>(count, rowptr, csr, out + 18, adjraw);
  k_graph<<<NB, 128, 0, stream>>>(out_pool, adjraw, den_g, ss_g, Wrel3, brel3, Wroot3,
                                  Wlin1, blin1, Wlin2, blin2, out, scratch);
  k_final<<<1, 64, 0, stream>>>(scratch, out);
}

// Round 14
// 212.715 us; speedup vs baseline: 1.4134x; 1.0564x over previous
//
#include <hip/hip_runtime.h>

// Problem constants (fixed by the reference)
#define NN     100000      // nodes
#define EE     1600000     // edges
#define NB     8           // graphs
#define BLK    12500       // nodes per graph
#define HID    128
#define KC     4
#define CHUNKS 196         // ceil(12500/64)
#define NTILE  49          // dst-ranges of 256 nodes per graph
#define NBIN   392         // 8 graphs x 49 tiles
#define GCAPS  5120        // per-bin capacity (mean 4081, sigma ~64)

typedef __attribute__((ext_vector_type(8))) short bf16x8;
typedef __attribute__((ext_vector_type(4))) float f32x4;

__device__ __forceinline__ ushort f2bf(float f) {
  uint u = __float_as_uint(f);
  return (ushort)((u + 0x7FFFu + ((u >> 16) & 1u)) >> 16);  // RNE
}
__device__ __forceinline__ float bf2f(ushort h) {
  return __uint_as_float(((uint)h) << 16);
}

#define GLL16(g, l) \
  __builtin_amdgcn_global_load_lds((const __attribute__((address_space(1))) void*)(g), \
                                   (__attribute__((address_space(3))) void*)(l), 16, 0, 0)

// ---------------------------------------------------------------- K0a: x -> bf16
__global__ __launch_bounds__(256) void k_prep_x(const float4* __restrict__ x4,
                                                ushort* __restrict__ xb) {
  int i = blockIdx.x * 256 + threadIdx.x;  // 3.2M float4s exactly
  float4 v = x4[i];
  ushort4 r;
  r.x = f2bf(v.x); r.y = f2bf(v.y); r.z = f2bf(v.z); r.w = f2bf(v.w);
  *(ushort4*)(xb + (size_t)i * 4) = r;
}

// ---------------------------------------------------------------- K0b: Wt[col][k], k<128 = Wrel1, k>=128 = Wroot1
__global__ __launch_bounds__(256) void k_prep_w(const float* __restrict__ Wrel1,
                                                const float* __restrict__ Wroot1,
                                                ushort* __restrict__ Wt) {
  int col = blockIdx.x, k = threadIdx.x;
  float v = (k < 128) ? Wrel1[k * 128 + col] : Wroot1[(k - 128) * 128 + col];
  Wt[col * 256 + k] = f2bf(v);
}

// ---------------------------------------------------------------- K1a: edges -> 392 (graph, dst-range) sub-buckets
__global__ __launch_bounds__(256) void k_bucket2(const int* __restrict__ ei,
                                                 int* __restrict__ sbcnt,
                                                 uint* __restrict__ gbuf) {
  __shared__ uint stage[8192];
  __shared__ int cnt[NBIN], start[NBIN + 1], rbase[NBIN];
  __shared__ int gtot[8], gb[8];
  const int t = threadIdx.x;
  for (int b = t; b < NBIN; b += 256) cnt[b] = 0;
  __syncthreads();
  const int e0 = blockIdx.x * 8192;
  uint pk[32]; int br[32];
#pragma unroll
  for (int i = 0; i < 32; ++i) {
    int e = e0 + i * 256 + t;
    bool val = (e < EE);
    int src = 0, dst = 0;
    if (val) {
      src = __builtin_nontemporal_load(ei + e);
      dst = __builtin_nontemporal_load(ei + EE + e);
    }
    int g = dst / BLK;
    int dl = dst - g * BLK;
    int sl = src - g * BLK;
    int bin = g * NTILE + (dl >> 8);
    pk[i] = ((uint)sl << 16) | (uint)dl;
    br[i] = val ? ((bin << 14) | atomicAdd(&cnt[bin], 1)) : -1;
  }
  __syncthreads();
  if (t < 8) {
    int s = 0;
    for (int k = 0; k < NTILE; ++k) s += cnt[t * NTILE + k];
    gtot[t] = s;
  }
  __syncthreads();
  if (t == 0) {
    int s = 0;
    for (int g = 0; g < 8; ++g) { gb[g] = s; s += gtot[g]; }
    start[NBIN] = s;
  }
  __syncthreads();
  if (t < 8) {
    int run = gb[t];
    for (int k = 0; k < NTILE; ++k) { start[t * NTILE + k] = run; run += cnt[t * NTILE + k]; }
  }
  __syncthreads();
  for (int b = t; b < NBIN; b += 256) rbase[b] = atomicAdd(&sbcnt[b], cnt[b]);
#pragma unroll
  for (int i = 0; i < 32; ++i) {
    if (br[i] >= 0) {
      int bin = br[i] >> 14, rank = br[i] & 16383;
      stage[start[bin] + rank] = pk[i];
    }
  }
  __syncthreads();
  const int total = start[NBIN];
  for (int j = t; j < total; j += 256) {
    int lo = 0, hi = NBIN - 1;  // largest bin with start[bin] <= j
    while (lo < hi) { int mid = (lo + hi + 1) >> 1; if (j >= start[mid]) lo = mid; else hi = mid - 1; }
    gbuf[(size_t)lo * GCAPS + rbase[lo] + (j - start[lo])] = stage[j];
  }
}

// ---------------------------------------------------------------- K1b: exclusive scan of bin sizes
__global__ __launch_bounds__(512) void k_scan392(const int* __restrict__ sbcnt,
                                                 int* __restrict__ sbbase) {
  __shared__ int sd[512];
  const int t = threadIdx.x;
  int v = (t < NBIN) ? sbcnt[t] : 0;
  sd[t] = v;
  __syncthreads();
  for (int s = 1; s < 512; s <<= 1) {
    int x = (t >= s) ? sd[t - s] : 0;
    __syncthreads();
    sd[t] += x;
    __syncthreads();
  }
  if (t < NBIN) sbbase[t] = sd[t] - v;
}

// ---------------------------------------------------------------- K1c: per-bin LDS counting sort -> dense CSR segment + rowptr + count
__global__ __launch_bounds__(256) void k_csr_tile(const uint* __restrict__ gbuf,
                                                  const int* __restrict__ sbcnt,
                                                  const int* __restrict__ sbbase,
                                                  int* __restrict__ rowptr,
                                                  int* __restrict__ count,
                                                  int* __restrict__ csr) {
  const int g = blockIdx.x & 7;     // XCD-local per graph
  const int tile = blockIdx.x >> 3; // 0..48
  const int bin = g * NTILE + tile;
  const int m = sbcnt[bin];
  const int base = sbbase[bin];
  const int n0t = tile * 256;
  const int nt = min(256, BLK - n0t);
  __shared__ uint ent[GCAPS];
  __shared__ ushort srt[GCAPS];
  __shared__ int cnt[256], scn[256], cur[256];
  const int t = threadIdx.x;
  cnt[t] = 0;
  __syncthreads();
  const uint* buf = gbuf + (size_t)bin * GCAPS;
  for (int i = t; i < m; i += 256) {
    uint pk = buf[i];
    ent[i] = pk;
    atomicAdd(&cnt[(int)(pk & 0xFFFFu) - n0t], 1);
  }
  __syncthreads();
  int v = cnt[t];
  scn[t] = v;
  __syncthreads();
  for (int s = 1; s < 256; s <<= 1) {
    int x = (t >= s) ? scn[t - s] : 0;
    __syncthreads();
    scn[t] += x;
    __syncthreads();
  }
  int excl = scn[t] - v;
  cur[t] = excl;
  if (t < nt) {
    rowptr[g * BLK + n0t + t] = base + excl;
    count[g * BLK + n0t + t] = v;
  }
  __syncthreads();
  for (int i = t; i < m; i += 256) {
    uint pk = ent[i];
    int p = atomicAdd(&cur[(int)(pk & 0xFFFFu) - n0t], 1);
    srt[p] = (ushort)(pk >> 16);
  }
  __syncthreads();
  const int nb = g * BLK;
  for (int i = t; i < m; i += 256)
    csr[base + i] = nb + (int)srt[i];  // dense coalesced
}

// ---------------------------------------------------------------- K2: agg[n] = sum_{e: dst=n} x[src]  (bf16, fp32 accum, 4-way unroll)
__global__ __launch_bounds__(256) void k_agg2(const ushort* __restrict__ xb,
                                              const int* __restrict__ count,
                                              const int* __restrict__ rowptr,
                                              const int* __restrict__ csr,
                                              ushort* __restrict__ aggb) {
  const int xg = blockIdx.x & 7;
  const int j = blockIdx.x >> 3;
  const int half = threadIdx.x >> 5;  // 8 half-waves = 8 nodes per block
  const int lane = threadIdx.x & 31;
  const int ln = j * 8 + half;
  if (ln >= BLK) return;
  const int node = xg * BLK + ln;
  const int deg = count[node];
  const int* sl = csr + rowptr[node];
  int idx0 = (lane < deg) ? sl[lane] : 0;
  int idx1 = (32 + lane < deg) ? sl[32 + lane] : 0;

#define GETIDX(e) ((e) < 32 ? __shfl(idx0, (e), 32) \
                            : ((e) < 64 ? __shfl(idx1, (e) - 32, 32) : sl[(e)]))

  float A0 = 0.f, A1 = 0.f, A2 = 0.f, A3 = 0.f;
  float B0 = 0.f, B1 = 0.f, B2 = 0.f, B3 = 0.f;
  float C0 = 0.f, C1 = 0.f, C2 = 0.f, C3 = 0.f;
  float D0 = 0.f, D1 = 0.f, D2 = 0.f, D3 = 0.f;
  int e = 0;
  for (; e + 4 <= deg; e += 4) {
    int s0 = GETIDX(e + 0);
    int s1 = GETIDX(e + 1);
    int s2 = GETIDX(e + 2);
    int s3 = GETIDX(e + 3);
    ushort4 v0 = *(const ushort4*)(xb + (size_t)s0 * HID + lane * 4);
    ushort4 v1 = *(const ushort4*)(xb + (size_t)s1 * HID + lane * 4);
    ushort4 v2 = *(const ushort4*)(xb + (size_t)s2 * HID + lane * 4);
    ushort4 v3 = *(const ushort4*)(xb + (size_t)s3 * HID + lane * 4);
    A0 += bf2f(v0.x); A1 += bf2f(v0.y); A2 += bf2f(v0.z); A3 += bf2f(v0.w);
    B0 += bf2f(v1.x); B1 += bf2f(v1.y); B2 += bf2f(v1.z); B3 += bf2f(v1.w);
    C0 += bf2f(v2.x); C1 += bf2f(v2.y); C2 += bf2f(v2.z); C3 += bf2f(v2.w);
    D0 += bf2f(v3.x); D1 += bf2f(v3.y); D2 += bf2f(v3.z); D3 += bf2f(v3.w);
  }
  for (; e < deg; ++e) {
    int s0 = GETIDX(e);
    ushort4 v0 = *(const ushort4*)(xb + (size_t)s0 * HID + lane * 4);
    A0 += bf2f(v0.x); A1 += bf2f(v0.y); A2 += bf2f(v0.z); A3 += bf2f(v0.w);
  }
#undef GETIDX

  ushort* dstp = aggb + (size_t)node * HID + lane * 4;
  ushort4 r;
  r.x = f2bf(A0 + B0 + C0 + D0);
  r.y = f2bf(A1 + B1 + C1 + D1);
  r.z = f2bf(A2 + B2 + C2 + D2);
  r.w = f2bf(A3 + B3 + C3 + D3);
  *(ushort4*)dstp = r;
}

// ---------------------------------------------------------------- K3: MFMA GEMM + softmax + pooled reductions
// R14: A staging via global_load_lds async DMA (no VGPR cost -> 32 KB in
// flight per block, HBM latency covered; R7-R13 showed the compiler caps
// VGPR at ~68 and serializes VMEM into ~1.4 loads/wave). Linear LDS dest +
// pre-swizzled global source (boff ^= (row&7)<<4), read back with the same
// XOR -> 2-way bank aliasing (free) instead of 16-way.
__global__ __launch_bounds__(256) void k_fused(
    const ushort* __restrict__ aggb, const ushort* __restrict__ xb,
    const ushort* __restrict__ Wt, const float* __restrict__ brel1,
    const float* __restrict__ Wpool, const float* __restrict__ bpool,
    const int* __restrict__ count, float* __restrict__ s_out,
    float* __restrict__ out_pool, float* __restrict__ ss_g,
    float* __restrict__ den_g) {
  __shared__ ushort Aag_s[64][128];  // 16 KB, linear (DMA dest)
  __shared__ ushort Ax_s[64][128];   // 16 KB, linear (DMA dest)
  __shared__ ushort hLb[64][136];    // h tile bf16 (pad 136)
  __shared__ float outL[KC][HID];
  __shared__ float ssL[16];
  __shared__ float denL;

  const int t = threadIdx.x;
  const int bi = blockIdx.x;
  const int bG = bi & 7;            // graph = XCD (round-robin)
  const int chunk = bi >> 3;
  const int node0 = bG * BLK + chunk * 64;
  int nrows = BLK - chunk * 64;
  if (nrows > 64) nrows = 64;

  const int w = t >> 6;     // wave: cols 32w..32w+31
  const int l = t & 63;

  // ---- async stage: 8 global_load_lds per wave (4 agg + 4 x tiles) ----
  {
    const int sub = l >> 4;          // row within 4-row group
    const int c16 = l & 15;          // 16B chunk within row
#pragma unroll
    for (int i = 0; i < 4; ++i) {
      const int j = w * 4 + i;       // 0..15: rows 4j..4j+3
      const int row = j * 4 + sub;
      const int rs = (row < nrows) ? row : (nrows - 1);  // clamp source row
      const int boff = (c16 * 16) ^ ((row & 7) << 4);    // swizzled src col
      const ushort* ga = aggb + (size_t)(node0 + rs) * HID + (boff >> 1);
      const ushort* gx = xb + (size_t)(node0 + rs) * HID + (boff >> 1);
      GLL16(ga, &Aag_s[j * 4][0]);
      GLL16(gx, &Ax_s[j * 4][0]);
    }
  }

  for (int i = t; i < KC * HID; i += 256) ((float*)outL)[i] = 0.f;
  if (t < 16) ssL[t] = 0.f;
  if (t == 0) denL = 0.f;

  const int m16 = l & 15;
  const int gq = l >> 4;

  // ---- B fragments: registers/L2 (Wt 64 KB, hot) ----
  bf16x8 Breg[8][2];
#pragma unroll
  for (int kt = 0; kt < 8; ++kt)
#pragma unroll
    for (int fc = 0; fc < 2; ++fc)
      Breg[kt][fc] =
          *(const bf16x8*)(Wt + (size_t)(32 * w + 16 * fc + m16) * 256 + kt * 32 + 8 * gq);

  f32x4 acc[4][2];
#pragma unroll
  for (int fr = 0; fr < 4; ++fr)
#pragma unroll
    for (int fc = 0; fc < 2; ++fc) acc[fr][fc] = (f32x4){0.f, 0.f, 0.f, 0.f};

  asm volatile("s_waitcnt vmcnt(0)" ::: "memory");
  __syncthreads();

#pragma unroll
  for (int kt = 0; kt < 8; ++kt) {
    const int k4 = kt & 3;
    bf16x8 af[4];
#pragma unroll
    for (int fr = 0; fr < 4; ++fr) {
      const int r = 16 * fr + m16;
      const int ci = (k4 * 32 + gq * 8) ^ ((r & 7) << 3);  // swizzled ushort idx
      af[fr] = (kt < 4) ? *(const bf16x8*)&Aag_s[r][ci]
                        : *(const bf16x8*)&Ax_s[r][ci];
    }
#pragma unroll
    for (int fr = 0; fr < 4; ++fr)
#pragma unroll
      for (int fc = 0; fc < 2; ++fc)
        acc[fr][fc] = __builtin_amdgcn_mfma_f32_16x16x32_bf16(af[fr], Breg[kt][fc],
                                                              acc[fr][fc], 0, 0, 0);
  }

  // bias + relu -> hLb (bf16)  (D layout: row = 4*(l>>4)+reg, col = l&15 [m89])
  const float bc0 = brel1[32 * w + m16];
  const float bc1 = brel1[32 * w + 16 + m16];
#pragma unroll
  for (int fr = 0; fr < 4; ++fr)
#pragma unroll
    for (int fc = 0; fc < 2; ++fc)
#pragma unroll
      for (int r = 0; r < 4; ++r)
        hLb[16 * fr + 4 * gq + r][32 * w + 16 * fc + m16] =
            f2bf(fmaxf(acc[fr][fc][r] + (fc ? bc1 : bc0), 0.f));
  __syncthreads();

  // ---- epilogue (16-lane groups own 4 rows each) ----
  const int g4 = t >> 4;
  const int c0 = (t & 15) << 2;
  const int li = t & 15;

  float h[4][8];
#pragma unroll
  for (int r = 0; r < 4; ++r) {
    ushort4 v0 = *(const ushort4*)&hLb[g4 * 4 + r][c0];
    ushort4 v1 = *(const ushort4*)&hLb[g4 * 4 + r][c0 + 64];
    h[r][0] = bf2f(v0.x); h[r][1] = bf2f(v0.y); h[r][2] = bf2f(v0.z); h[r][3] = bf2f(v0.w);
    h[r][4] = bf2f(v1.x); h[r][5] = bf2f(v1.y); h[r][6] = bf2f(v1.z); h[r][7] = bf2f(v1.w);
  }

  // pooling head: p = h @ Wpool
  float wp[8][4];
#pragma unroll
  for (int j = 0; j < 8; ++j) {
    int col = c0 + (j & 3) + (j >> 2) * 64;
    float4 v = *(const float4*)(Wpool + col * 4);
    wp[j][0] = v.x; wp[j][1] = v.y; wp[j][2] = v.z; wp[j][3] = v.w;
  }
  float pp[4][4];
#pragma unroll
  for (int r = 0; r < 4; ++r)
#pragma unroll
    for (int k = 0; k < 4; ++k) pp[r][k] = 0.f;
#pragma unroll
  for (int r = 0; r < 4; ++r)
#pragma unroll
    for (int j = 0; j < 8; ++j)
#pragma unroll
      for (int k = 0; k < 4; ++k) pp[r][k] = fmaf(h[r][j], wp[j][k], pp[r][k]);
#pragma unroll
  for (int m = 1; m <= 8; m <<= 1)
#pragma unroll
    for (int r = 0; r < 4; ++r)
#pragma unroll
      for (int k = 0; k < 4; ++k) pp[r][k] += __shfl_xor(pp[r][k], m);

  float4 bp4 = *(const float4*)bpool;
  float bp[4] = {bp4.x, bp4.y, bp4.z, bp4.w};
  float sv[4][4];
#pragma unroll
  for (int r = 0; r < 4; ++r) {
    float p[4];
#pragma unroll
    for (int k = 0; k < 4; ++k) p[k] = pp[r][k] + bp[k];
    float mx = fmaxf(fmaxf(p[0], p[1]), fmaxf(p[2], p[3]));
    float e0 = expf(p[0] - mx), e1 = expf(p[1] - mx), e2 = expf(p[2] - mx), e3 = expf(p[3] - mx);
    float inv = 1.f / (e0 + e1 + e2 + e3);
    float valid = (g4 * 4 + r < nrows) ? 1.f : 0.f;
    sv[r][0] = e0 * inv * valid; sv[r][1] = e1 * inv * valid;
    sv[r][2] = e2 * inv * valid; sv[r][3] = e3 * inv * valid;
  }

  // write s
  {
    int rW = li >> 2, kW = li & 3;
    if (g4 * 4 + rW < nrows) {
      int node = node0 + g4 * 4 + rW;
      float val = 0.f;
#pragma unroll
      for (int rr = 0; rr < 4; ++rr)
#pragma unroll
        for (int kk = 0; kk < 4; ++kk)
          if (li == rr * 4 + kk) val = sv[rr][kk];
      s_out[node * 4 + kW] = val;
    }
  }

  // ss[b][k1][k2]
  {
    int k1 = li >> 2, k2 = li & 3;
    float a1[4], a2[4];
#pragma unroll
    for (int rr = 0; rr < 4; ++rr) {
      float v1 = 0.f, v2 = 0.f;
#pragma unroll
      for (int kk = 0; kk < 4; ++kk) {
        if (k1 == kk) v1 = sv[rr][kk];
        if (k2 == kk) v2 = sv[rr][kk];
      }
      a1[rr] = v1; a2[rr] = v2;
    }
    float ssv = a1[0] * a2[0] + a1[1] * a2[1] + a1[2] * a2[2] + a1[3] * a2[3];
    atomicAdd(&ssL[li], ssv);
  }

  // den += deg * ||s||^2
  if (li == 0) {
    float dent = 0.f;
#pragma unroll
    for (int rr = 0; rr < 4; ++rr) {
      int rowg = g4 * 4 + rr;
      if (rowg < nrows) {
        float dg = (float)count[node0 + rowg];
        dent += dg * (sv[rr][0] * sv[rr][0] + sv[rr][1] * sv[rr][1] +
                      sv[rr][2] * sv[rr][2] + sv[rr][3] * sv[rr][3]);
      }
    }
    atomicAdd(&denL, dent);
  }

  // out[k][c] += s[r][k]*h[r][c]
  float po[4][8];
#pragma unroll
  for (int k = 0; k < 4; ++k)
#pragma unroll
    for (int c = 0; c < 8; ++c) po[k][c] = 0.f;
#pragma unroll
  for (int k = 0; k < 4; ++k)
#pragma unroll
    for (int rr = 0; rr < 4; ++rr)
#pragma unroll
      for (int c = 0; c < 8; ++c) po[k][c] = fmaf(sv[rr][k], h[rr][c], po[k][c]);
#pragma unroll
  for (int k = 0; k < 4; ++k)
#pragma unroll
    for (int c = 0; c < 8; ++c) {
      po[k][c] += __shfl_xor(po[k][c], 16);
      po[k][c] += __shfl_xor(po[k][c], 32);
    }
  if ((t & 63) < 16) {
#pragma unroll
    for (int k = 0; k < 4; ++k)
#pragma unroll
      for (int c = 0; c < 8; ++c)
        atomicAdd(&outL[k][c0 + (c & 3) + (c >> 2) * 64], po[k][c]);
  }

  __syncthreads();
  for (int i = t; i < KC * HID; i += 256)
    atomicAdd(&out_pool[bG * KC * HID + i], ((const float*)outL)[i]);
  if (t < 16) atomicAdd(&ss_g[bG * 16 + t], ssL[t]);
  if (t == 0) atomicAdd(&den_g[bG], denL);
}

// ---------------------------------------------------------------- K4: out_adj[b] = sum_n s[n] (x) t[n]  (4-way unroll)
__global__ __launch_bounds__(256) void k_adj2(const int* __restrict__ count,
                                              const int* __restrict__ rowptr,
                                              const int* __restrict__ csr,
                                              const float* __restrict__ s,
                                              float* __restrict__ adjraw) {
  __shared__ float accL[4][2][16];  // [wave][graph-within-block][k1*4+k2]
  const int t = threadIdx.x;
  if (t < 128) ((float*)accL)[t] = 0.f;
  __syncthreads();
  const int node = blockIdx.x * 256 + t;
  const int g0 = (blockIdx.x * 256) / BLK;
  if (node < NN) {
    const int gi = node / BLK - g0;  // 0 or 1
    const int deg = count[node];
    const int* sl = csr + rowptr[node];
    float A0 = 0.f, A1 = 0.f, A2 = 0.f, A3 = 0.f;
    float B0 = 0.f, B1 = 0.f, B2 = 0.f, B3 = 0.f;
    float C0 = 0.f, C1 = 0.f, C2 = 0.f, C3 = 0.f;
    float D0 = 0.f, D1 = 0.f, D2 = 0.f, D3 = 0.f;
    int e = 0;
    for (; e + 4 <= deg; e += 4) {
      int s0 = sl[e + 0], s1 = sl[e + 1], s2 = sl[e + 2], s3 = sl[e + 3];
      float4 v0 = *(const float4*)(s + (size_t)s0 * 4);
      float4 v1 = *(const float4*)(s + (size_t)s1 * 4);
      float4 v2 = *(const float4*)(s + (size_t)s2 * 4);
      float4 v3 = *(const float4*)(s + (size_t)s3 * 4);
      A0 += v0.x; A1 += v0.y; A2 += v0.z; A3 += v0.w;
      B0 += v1.x; B1 += v1.y; B2 += v1.z; B3 += v1.w;
      C0 += v2.x; C1 += v2.y; C2 += v2.z; C3 += v2.w;
      D0 += v3.x; D1 += v3.y; D2 += v3.z; D3 += v3.w;
    }
    for (; e < deg; ++e) {
      float4 v0 = *(const float4*)(s + (size_t)sl[e] * 4);
      A0 += v0.x; A1 += v0.y; A2 += v0.z; A3 += v0.w;
    }
    float t0 = A0 + B0 + C0 + D0;
    float t1 = A1 + B1 + C1 + D1;
    float t2 = A2 + B2 + C2 + D2;
    float t3 = A3 + B3 + C3 + D3;
    float4 sn = *(const float4*)(s + (size_t)node * 4);
    float* base = accL[t >> 6][gi];
#pragma unroll
    for (int i = 0; i < 16; ++i) {
      int idx = (i + t) & 15;  // stagger: 4-way instead of 64-way contention
      int hi = idx >> 2, lo = idx & 3;
      float a = (hi == 0) ? sn.x : (hi == 1) ? sn.y : (hi == 2) ? sn.z : sn.w;
      float b = (lo == 0) ? t0 : (lo == 1) ? t1 : (lo == 2) ? t2 : t3;
      atomicAdd(base + idx, a * b);
    }
  }
  __syncthreads();
  if (t < 32) {
    int gi = t >> 4, i = t & 15, gg = g0 + gi;
    if (gg < NB) {
      float v = accL[0][gi][i] + accL[1][gi][i] + accL[2][gi][i] + accL[3][gi][i];
      atomicAdd(&adjraw[gg * 16 + i], v);
    }
  }
}

// ---------------------------------------------------------------- K5a: per-graph tail
__global__ __launch_bounds__(128) void k_graph(
    const float* __restrict__ out_pool, const float* __restrict__ adjraw,
    const float* __restrict__ den_g, const float* __restrict__ ss_g,
    const float* __restrict__ Wrel3, const float* __restrict__ brel3,
    const float* __restrict__ Wroot3, const float* __restrict__ Wlin1,
    const float* __restrict__ blin1, const float* __restrict__ Wlin2,
    const float* __restrict__ blin2, float* __restrict__ d_out,
    float* __restrict__ scratch) {
  const int b = blockIdx.x, t = threadIdx.x;
  __shared__ float adjL[16], adjnL[16], dL[4];
  __shared__ float osL[128], msL[128], x2mL[128], x3L[128];
  if (t < 16) adjL[t] = adjraw[b * 16 + t];
  __syncthreads();
  if (t < 4) {
    float srow = 0.f;
#pragma unroll
    for (int l = 0; l < 4; ++l)
      if (l != t) srow += adjL[t * 4 + l];
    dL[t] = sqrtf(srow) + 1e-15f;
  }
  __syncthreads();
  if (t < 16) {
    int k1 = t >> 2, k2 = t & 3;
    float az = (k1 == k2) ? 0.f : adjL[t];
    float an = az / (dL[k2] * dL[k1]);
    adjnL[t] = an;
    d_out[400018 + b * 16 + t] = an;
  }
  __syncthreads();
  float o0 = out_pool[b * 512 + 0 * 128 + t];
  float o1 = out_pool[b * 512 + 1 * 128 + t];
  float o2 = out_pool[b * 512 + 2 * 128 + t];
  float o3 = out_pool[b * 512 + 3 * 128 + t];
  float m0 = adjnL[0] * o0 + adjnL[1] * o1 + adjnL[2] * o2 + adjnL[3] * o3;
  float m1 = adjnL[4] * o0 + adjnL[5] * o1 + adjnL[6] * o2 + adjnL[7] * o3;
  float m2 = adjnL[8] * o0 + adjnL[9] * o1 + adjnL[10] * o2 + adjnL[11] * o3;
  float m3 = adjnL[12] * o0 + adjnL[13] * o1 + adjnL[14] * o2 + adjnL[15] * o3;
  osL[t] = o0 + o1 + o2 + o3;
  msL[t] = m0 + m1 + m2 + m3;
  __syncthreads();
  float accc = brel3[t];
  for (int j = 0; j < 128; ++j)
    accc += 0.25f * (msL[j] * Wrel3[j * 128 + t] + osL[j] * Wroot3[j * 128 + t]);
  x2mL[t] = accc;
  __syncthreads();
  float a2 = blin1[t];
  for (int j = 0; j < 128; ++j) a2 += x2mL[j] * Wlin1[j * 128 + t];
  x3L[t] = fmaxf(a2, 0.f);
  __syncthreads();
  if (t < 2) {
    float lg = blin2[t];
    for (int j = 0; j < 128; ++j) lg += x3L[j] * Wlin2[j * 2 + t];
    scratch[b * 2 + t] = lg;
  }
  if (t == 0) {
    float tr = adjL[0] + adjL[5] + adjL[10] + adjL[15];
    scratch[16 + b] = tr / den_g[b];
    float n2 = 0.f;
    for (int i = 0; i < 16; ++i) { float v = ss_g[b * 16 + i]; n2 += v * v; }
    float nn = sqrtf(n2);
    float od = 0.f;
    for (int i = 0; i < 16; ++i) {
      float v = ss_g[b * 16 + i] / nn - (((i >> 2) == (i & 3)) ? 0.5f : 0.f);
      od += v * v;
    }
    scratch[24 + b] = sqrtf(od);
  }
}

// ---------------------------------------------------------------- K5b: losses + log_softmax
__global__ void k_final(const float* __restrict__ scratch, float* __restrict__ d_out) {
  if (threadIdx.x == 0 && blockIdx.x == 0) {
    float mc = 0.f, oo = 0.f;
    for (int b = 0; b < NB; ++b) { mc += scratch[16 + b]; oo += scratch[24 + b]; }
    d_out[16] = -(mc / (float)NB);
    d_out[17] = oo / (float)NB;
    for (int b = 0; b < NB; ++b) {
      float l0 = scratch[2 * b], l1 = scratch[2 * b + 1];
      float m = fmaxf(l0, l1);
      float lse = m + logf(expf(l0 - m) + expf(l1 - m));
      d_out[2 * b] = l0 - lse;
      d_out[2 * b + 1] = l1 - lse;
    }
  }
}

// ---------------------------------------------------------------- launch
extern "C" void kernel_launch(void* const* d_in, const int* in_sizes, int n_in,
                              void* d_out, int out_size, void* d_ws, size_t ws_size,
                              hipStream_t stream) {
  (void)in_sizes; (void)n_in; (void)out_size; (void)ws_size;
  const float* x      = (const float*)d_in[0];
  const int*   ei     = (const int*)d_in[1];
  const float* Wroot1 = (const float*)d_in[3];
  const float* Wrel1  = (const float*)d_in[4];
  const float* brel1  = (const float*)d_in[5];
  const float* Wpool  = (const float*)d_in[6];
  const float* bpool  = (const float*)d_in[7];
  const float* Wrel3  = (const float*)d_in[8];
  const float* brel3  = (const float*)d_in[9];
  const float* Wroot3 = (const float*)d_in[10];
  const float* Wlin1  = (const float*)d_in[11];
  const float* blin1  = (const float*)d_in[12];
  const float* Wlin2  = (const float*)d_in[13];
  const float* blin2  = (const float*)d_in[14];
  float* out = (float*)d_out;

  char* ws = (char*)d_ws;
  float*  out_pool = (float*)(ws + 0);          //  16384 B (memset)
  float*  ss_g     = (float*)(ws + 16384);      //    512 B (memset)
  float*  adjraw   = (float*)(ws + 16896);      //    512 B (memset)
  float*  den_g    = (float*)(ws + 17408);      //     32 B (memset)
  float*  scratch  = (float*)(ws + 17440);      //    128 B (memset)
  int*    sbcnt    = (int*)(ws + 17568);        //   1568 B (memset)
  int*    sbbase   = (int*)(ws + 19136);        //   1600 B
  int*    count    = (int*)(ws + 20736);        // 400000 B
  int*    rowptr   = (int*)(ws + 420736);       // 400016 B
  ushort* Wt       = (ushort*)(ws + 820752);    //  65536 B [128][256]
  int*    csr      = (int*)(ws + 886288);       // 6400000 B [E]
  ushort* xb       = (ushort*)(ws + 7286288);   // 25600000 B [N][128] bf16
  ushort* aggb     = (ushort*)(ws + 32886288);  // 25600000 B [N][128] bf16
  uint*   gbuf     = (uint*)(ws + 58486288);    // 8028160 B

  hipMemsetAsync(ws, 0, 19136, stream);
  k_prep_x<<<12500, 256, 0, stream>>>((const float4*)x, xb);
  k_prep_w<<<128, 256, 0, stream>>>(Wrel1, Wroot1, Wt);
  k_bucket2<<<196, 256, 0, stream>>>(ei, sbcnt, gbuf);
  k_scan392<<<1, 512, 0, stream>>>(sbcnt, sbbase);
  k_csr_tile<<<NBIN, 256, 0, stream>>>(gbuf, sbcnt, sbbase, rowptr, count, csr);
  k_agg2<<<8 * ((BLK + 7) / 8), 256, 0, stream>>>(xb, count, rowptr, csr, aggb);
  k_fused<<<NB * CHUNKS, 256, 0, stream>>>(aggb, xb, Wt, brel1, Wpool, bpool, count,
                                           out + 18, out_pool, ss_g, den_g);
  k_adj2<<<(NN + 255) / 256, 256, 0, stream>>>(count, rowptr, csr, out + 18, adjraw);
  k_graph<<<NB, 128, 0, stream>>>(out_pool, adjraw, den_g, ss_g, Wrel3, brel3, Wroot3,
                                  Wlin1, blin1, Wlin2, blin2, out, scratch);
  k_final<<<1, 64, 0, stream>>>(scratch, out);
}

// Round 15
// 209.833 us; speedup vs baseline: 1.4328x; 1.0137x over previous
//
#include <hip/hip_runtime.h>

// Problem constants (fixed by the reference)
#define NN     100000      // nodes
#define EE     1600000     // edges
#define NB     8           // graphs
#define BLK    12500       // nodes per graph
#define HID    128
#define KC     4
#define CHUNKS 196         // ceil(12500/64)
#define NTILE  49          // dst-ranges of 256 nodes per graph
#define NBIN   392         // 8 graphs x 49 tiles
#define GCAPS  5120        // per-bin capacity (mean 4081, sigma ~64)

typedef __attribute__((ext_vector_type(8))) short bf16x8;
typedef __attribute__((ext_vector_type(4))) float f32x4;

__device__ __forceinline__ ushort f2bf(float f) {
  uint u = __float_as_uint(f);
  return (ushort)((u + 0x7FFFu + ((u >> 16) & 1u)) >> 16);  // RNE
}
__device__ __forceinline__ float bf2f(ushort h) {
  return __uint_as_float(((uint)h) << 16);
}

#define GLL16(g, l) \
  __builtin_amdgcn_global_load_lds((const __attribute__((address_space(1))) void*)(g), \
                                   (__attribute__((address_space(3))) void*)(l), 16, 0, 0)

// ---------------------------------------------------------------- K0a: x -> bf16
__global__ __launch_bounds__(256) void k_prep_x(const float4* __restrict__ x4,
                                                ushort* __restrict__ xb) {
  int i = blockIdx.x * 256 + threadIdx.x;  // 3.2M float4s exactly
  float4 v = x4[i];
  ushort4 r;
  r.x = f2bf(v.x); r.y = f2bf(v.y); r.z = f2bf(v.z); r.w = f2bf(v.w);
  *(ushort4*)(xb + (size_t)i * 4) = r;
}

// ---------------------------------------------------------------- K0b: Wt[col][k], k<128 = Wrel1, k>=128 = Wroot1
__global__ __launch_bounds__(256) void k_prep_w(const float* __restrict__ Wrel1,
                                                const float* __restrict__ Wroot1,
                                                ushort* __restrict__ Wt) {
  int col = blockIdx.x, k = threadIdx.x;
  float v = (k < 128) ? Wrel1[k * 128 + col] : Wroot1[(k - 128) * 128 + col];
  Wt[col * 256 + k] = f2bf(v);
}

// ---------------------------------------------------------------- K1a: edges -> 392 (graph, dst-range) sub-buckets
// R15: flush via per-bin segmented copy (contiguous LDS reads + contiguous
// global writes) instead of a 9-step binary search per element.
__global__ __launch_bounds__(256) void k_bucket2(const int* __restrict__ ei,
                                                 int* __restrict__ sbcnt,
                                                 uint* __restrict__ gbuf) {
  __shared__ uint stage[8192];
  __shared__ int cnt[NBIN], start[NBIN + 1], rbase[NBIN];
  __shared__ int gtot[8], gb[8];
  const int t = threadIdx.x;
  for (int b = t; b < NBIN; b += 256) cnt[b] = 0;
  __syncthreads();
  const int e0 = blockIdx.x * 8192;
  uint pk[32]; int br[32];
#pragma unroll
  for (int i = 0; i < 32; ++i) {
    int e = e0 + i * 256 + t;
    bool val = (e < EE);
    int src = 0, dst = 0;
    if (val) {
      src = __builtin_nontemporal_load(ei + e);
      dst = __builtin_nontemporal_load(ei + EE + e);
    }
    int g = dst / BLK;
    int dl = dst - g * BLK;
    int sl = src - g * BLK;
    int bin = g * NTILE + (dl >> 8);
    pk[i] = ((uint)sl << 16) | (uint)dl;
    br[i] = val ? ((bin << 14) | atomicAdd(&cnt[bin], 1)) : -1;
  }
  __syncthreads();
  if (t < 8) {
    int s = 0;
    for (int k = 0; k < NTILE; ++k) s += cnt[t * NTILE + k];
    gtot[t] = s;
  }
  __syncthreads();
  if (t == 0) {
    int s = 0;
    for (int g = 0; g < 8; ++g) { gb[g] = s; s += gtot[g]; }
    start[NBIN] = s;
  }
  __syncthreads();
  if (t < 8) {
    int run = gb[t];
    for (int k = 0; k < NTILE; ++k) { start[t * NTILE + k] = run; run += cnt[t * NTILE + k]; }
  }
  __syncthreads();
  for (int b = t; b < NBIN; b += 256) rbase[b] = atomicAdd(&sbcnt[b], cnt[b]);
#pragma unroll
  for (int i = 0; i < 32; ++i) {
    if (br[i] >= 0) {
      int bin = br[i] >> 14, rank = br[i] & 16383;
      stage[start[bin] + rank] = pk[i];
    }
  }
  __syncthreads();
  // per-bin segmented flush
  for (int b = t; b < NBIN; b += 256) {
    const int n = cnt[b];
    const int s0 = start[b];
    uint* dst = gbuf + (size_t)b * GCAPS + rbase[b];
    for (int i = 0; i < n; ++i) dst[i] = stage[s0 + i];
  }
}

// ---------------------------------------------------------------- K1b: exclusive scan of bin sizes
__global__ __launch_bounds__(512) void k_scan392(const int* __restrict__ sbcnt,
                                                 int* __restrict__ sbbase) {
  __shared__ int sd[512];
  const int t = threadIdx.x;
  int v = (t < NBIN) ? sbcnt[t] : 0;
  sd[t] = v;
  __syncthreads();
  for (int s = 1; s < 512; s <<= 1) {
    int x = (t >= s) ? sd[t - s] : 0;
    __syncthreads();
    sd[t] += x;
    __syncthreads();
  }
  if (t < NBIN) sbbase[t] = sd[t] - v;
}

// ---------------------------------------------------------------- K1c: per-bin LDS counting sort -> dense CSR segment + rowptr + count
__global__ __launch_bounds__(256) void k_csr_tile(const uint* __restrict__ gbuf,
                                                  const int* __restrict__ sbcnt,
                                                  const int* __restrict__ sbbase,
                                                  int* __restrict__ rowptr,
                                                  int* __restrict__ count,
                                                  int* __restrict__ csr) {
  const int g = blockIdx.x & 7;     // XCD-local per graph
  const int tile = blockIdx.x >> 3; // 0..48
  const int bin = g * NTILE + tile;
  const int m = sbcnt[bin];
  const int base = sbbase[bin];
  const int n0t = tile * 256;
  const int nt = min(256, BLK - n0t);
  __shared__ uint ent[GCAPS];
  __shared__ ushort srt[GCAPS];
  __shared__ int cnt[256], scn[256], cur[256];
  const int t = threadIdx.x;
  cnt[t] = 0;
  __syncthreads();
  const uint* buf = gbuf + (size_t)bin * GCAPS;
  for (int i = t; i < m; i += 256) {
    uint pk = buf[i];
    ent[i] = pk;
    atomicAdd(&cnt[(int)(pk & 0xFFFFu) - n0t], 1);
  }
  __syncthreads();
  int v = cnt[t];
  scn[t] = v;
  __syncthreads();
  for (int s = 1; s < 256; s <<= 1) {
    int x = (t >= s) ? scn[t - s] : 0;
    __syncthreads();
    scn[t] += x;
    __syncthreads();
  }
  int excl = scn[t] - v;
  cur[t] = excl;
  if (t < nt) {
    rowptr[g * BLK + n0t + t] = base + excl;
    count[g * BLK + n0t + t] = v;
  }
  __syncthreads();
  for (int i = t; i < m; i += 256) {
    uint pk = ent[i];
    int p = atomicAdd(&cur[(int)(pk & 0xFFFFu) - n0t], 1);
    srt[p] = (ushort)(pk >> 16);
  }
  __syncthreads();
  const int nb = g * BLK;
  for (int i = t; i < m; i += 256)
    csr[base + i] = nb + (int)srt[i];  // dense coalesced
}

// ---------------------------------------------------------------- K2: agg[n] = sum_{e: dst=n} x[src]  (bf16, fp32 accum, 8-way unroll)
__global__ __launch_bounds__(256) void k_agg2(const ushort* __restrict__ xb,
                                              const int* __restrict__ count,
                                              const int* __restrict__ rowptr,
                                              const int* __restrict__ csr,
                                              ushort* __restrict__ aggb) {
  const int xg = blockIdx.x & 7;
  const int j = blockIdx.x >> 3;
  const int half = threadIdx.x >> 5;  // 8 half-waves = 8 nodes per block
  const int lane = threadIdx.x & 31;
  const int ln = j * 8 + half;
  if (ln >= BLK) return;
  const int node = xg * BLK + ln;
  const int deg = count[node];
  const int* sl = csr + rowptr[node];
  int idx0 = (lane < deg) ? sl[lane] : 0;
  int idx1 = (32 + lane < deg) ? sl[32 + lane] : 0;

#define GETIDX(e) ((e) < 32 ? __shfl(idx0, (e), 32) \
                            : ((e) < 64 ? __shfl(idx1, (e) - 32, 32) : sl[(e)]))

  float acc[8][4];
#pragma unroll
  for (int q = 0; q < 8; ++q)
#pragma unroll
    for (int c = 0; c < 4; ++c) acc[q][c] = 0.f;

  int e = 0;
  for (; e + 8 <= deg; e += 8) {
    int si[8];
#pragma unroll
    for (int q = 0; q < 8; ++q) si[q] = GETIDX(e + q);
    ushort4 v[8];
#pragma unroll
    for (int q = 0; q < 8; ++q)
      v[q] = *(const ushort4*)(xb + (size_t)si[q] * HID + lane * 4);
#pragma unroll
    for (int q = 0; q < 8; ++q) {
      acc[q][0] += bf2f(v[q].x); acc[q][1] += bf2f(v[q].y);
      acc[q][2] += bf2f(v[q].z); acc[q][3] += bf2f(v[q].w);
    }
  }
  for (; e < deg; ++e) {
    int s0 = GETIDX(e);
    ushort4 v0 = *(const ushort4*)(xb + (size_t)s0 * HID + lane * 4);
    acc[0][0] += bf2f(v0.x); acc[0][1] += bf2f(v0.y);
    acc[0][2] += bf2f(v0.z); acc[0][3] += bf2f(v0.w);
  }
#undef GETIDX

  float r0 = 0.f, r1 = 0.f, r2 = 0.f, r3 = 0.f;
#pragma unroll
  for (int q = 0; q < 8; ++q) { r0 += acc[q][0]; r1 += acc[q][1]; r2 += acc[q][2]; r3 += acc[q][3]; }
  ushort4 r;
  r.x = f2bf(r0); r.y = f2bf(r1); r.z = f2bf(r2); r.w = f2bf(r3);
  *(ushort4*)(aggb + (size_t)node * HID + lane * 4) = r;
}

// ---------------------------------------------------------------- K3a: GEMM half — stage A (DMA) + MFMA + bias/relu -> hbuf (dense bf16)
__global__ __launch_bounds__(256) void k_gemm(
    const ushort* __restrict__ aggb, const ushort* __restrict__ xb,
    const ushort* __restrict__ Wt, const float* __restrict__ brel1,
    ushort* __restrict__ hbuf) {
  __shared__ ushort Aag_s[64][128];  // 16 KB, linear (DMA dest)
  __shared__ ushort Ax_s[64][128];   // 16 KB, linear (DMA dest)
  __shared__ ushort hLb[64][136];    // h tile bf16 (pad 136)

  const int t = threadIdx.x;
  const int bi = blockIdx.x;
  const int bG = bi & 7;
  const int chunk = bi >> 3;
  const int node0 = bG * BLK + chunk * 64;
  int nrows = BLK - chunk * 64;
  if (nrows > 64) nrows = 64;

  const int w = t >> 6;
  const int l = t & 63;

  // async stage: 8 global_load_lds per wave (4 agg + 4 x tiles)
  {
    const int sub = l >> 4;
    const int c16 = l & 15;
#pragma unroll
    for (int i = 0; i < 4; ++i) {
      const int j = w * 4 + i;
      const int row = j * 4 + sub;
      const int rs = (row < nrows) ? row : (nrows - 1);
      const int boff = (c16 * 16) ^ ((row & 7) << 4);
      const ushort* ga = aggb + (size_t)(node0 + rs) * HID + (boff >> 1);
      const ushort* gx = xb + (size_t)(node0 + rs) * HID + (boff >> 1);
      GLL16(ga, &Aag_s[j * 4][0]);
      GLL16(gx, &Ax_s[j * 4][0]);
    }
  }

  const int m16 = l & 15;
  const int gq = l >> 4;

  bf16x8 Breg[8][2];
#pragma unroll
  for (int kt = 0; kt < 8; ++kt)
#pragma unroll
    for (int fc = 0; fc < 2; ++fc)
      Breg[kt][fc] =
          *(const bf16x8*)(Wt + (size_t)(32 * w + 16 * fc + m16) * 256 + kt * 32 + 8 * gq);

  f32x4 acc[4][2];
#pragma unroll
  for (int fr = 0; fr < 4; ++fr)
#pragma unroll
    for (int fc = 0; fc < 2; ++fc) acc[fr][fc] = (f32x4){0.f, 0.f, 0.f, 0.f};

  asm volatile("s_waitcnt vmcnt(0)" ::: "memory");
  __syncthreads();

#pragma unroll
  for (int kt = 0; kt < 8; ++kt) {
    const int k4 = kt & 3;
    bf16x8 af[4];
#pragma unroll
    for (int fr = 0; fr < 4; ++fr) {
      const int r = 16 * fr + m16;
      const int ci = (k4 * 32 + gq * 8) ^ ((r & 7) << 3);
      af[fr] = (kt < 4) ? *(const bf16x8*)&Aag_s[r][ci]
                        : *(const bf16x8*)&Ax_s[r][ci];
    }
#pragma unroll
    for (int fr = 0; fr < 4; ++fr)
#pragma unroll
      for (int fc = 0; fc < 2; ++fc)
        acc[fr][fc] = __builtin_amdgcn_mfma_f32_16x16x32_bf16(af[fr], Breg[kt][fc],
                                                              acc[fr][fc], 0, 0, 0);
  }

  const float bc0 = brel1[32 * w + m16];
  const float bc1 = brel1[32 * w + 16 + m16];
#pragma unroll
  for (int fr = 0; fr < 4; ++fr)
#pragma unroll
    for (int fc = 0; fc < 2; ++fc)
#pragma unroll
      for (int r = 0; r < 4; ++r)
        hLb[16 * fr + 4 * gq + r][32 * w + 16 * fc + m16] =
            f2bf(fmaxf(acc[fr][fc][r] + (fc ? bc1 : bc0), 0.f));
  __syncthreads();

  // dense h store: thread t -> row t>>2, 64 B chunk (t&3)
  {
    const int row = t >> 2;
    const int ch = (t & 3) * 32;
    if (row < nrows) {
      ushort* dst = hbuf + (size_t)(node0 + row) * HID + ch;
      const ushort* src = &hLb[row][ch];
#pragma unroll
      for (int q = 0; q < 4; ++q)
        *(bf16x8*)(dst + q * 8) = *(const bf16x8*)(src + q * 8);
    }
  }
}

// ---------------------------------------------------------------- K3b: epilogue half — read h, softmax + pooled reductions
__global__ __launch_bounds__(256) void k_epi(
    const ushort* __restrict__ hbuf, const float* __restrict__ Wpool,
    const float* __restrict__ bpool, const int* __restrict__ count,
    float* __restrict__ s_out, float* __restrict__ out_pool,
    float* __restrict__ ss_g, float* __restrict__ den_g) {
  __shared__ ushort hLb[64][136];
  __shared__ float outL[KC][HID];
  __shared__ float ssL[16];
  __shared__ float denL;

  const int t = threadIdx.x;
  const int bi = blockIdx.x;
  const int bG = bi & 7;
  const int chunk = bi >> 3;
  const int node0 = bG * BLK + chunk * 64;
  int nrows = BLK - chunk * 64;
  if (nrows > 64) nrows = 64;

  // dense h load: thread t -> row t>>2, 64 B chunk (t&3)
  {
    const int row = t >> 2;
    const int ch = (t & 3) * 32;
    const int rs = (row < nrows) ? row : (nrows - 1);
    const ushort* src = hbuf + (size_t)(node0 + rs) * HID + ch;
    ushort* dst = &hLb[row][ch];
#pragma unroll
    for (int q = 0; q < 4; ++q)
      *(bf16x8*)(dst + q * 8) = *(const bf16x8*)(src + q * 8);
  }

  for (int i = t; i < KC * HID; i += 256) ((float*)outL)[i] = 0.f;
  if (t < 16) ssL[t] = 0.f;
  if (t == 0) denL = 0.f;
  __syncthreads();

  const int g4 = t >> 4;
  const int c0 = (t & 15) << 2;
  const int li = t & 15;

  float h[4][8];
#pragma unroll
  for (int r = 0; r < 4; ++r) {
    ushort4 v0 = *(const ushort4*)&hLb[g4 * 4 + r][c0];
    ushort4 v1 = *(const ushort4*)&hLb[g4 * 4 + r][c0 + 64];
    h[r][0] = bf2f(v0.x); h[r][1] = bf2f(v0.y); h[r][2] = bf2f(v0.z); h[r][3] = bf2f(v0.w);
    h[r][4] = bf2f(v1.x); h[r][5] = bf2f(v1.y); h[r][6] = bf2f(v1.z); h[r][7] = bf2f(v1.w);
  }

  // pooling head: p = h @ Wpool
  float wp[8][4];
#pragma unroll
  for (int j = 0; j < 8; ++j) {
    int col = c0 + (j & 3) + (j >> 2) * 64;
    float4 v = *(const float4*)(Wpool + col * 4);
    wp[j][0] = v.x; wp[j][1] = v.y; wp[j][2] = v.z; wp[j][3] = v.w;
  }
  float pp[4][4];
#pragma unroll
  for (int r = 0; r < 4; ++r)
#pragma unroll
    for (int k = 0; k < 4; ++k) pp[r][k] = 0.f;
#pragma unroll
  for (int r = 0; r < 4; ++r)
#pragma unroll
    for (int j = 0; j < 8; ++j)
#pragma unroll
      for (int k = 0; k < 4; ++k) pp[r][k] = fmaf(h[r][j], wp[j][k], pp[r][k]);
#pragma unroll
  for (int m = 1; m <= 8; m <<= 1)
#pragma unroll
    for (int r = 0; r < 4; ++r)
#pragma unroll
      for (int k = 0; k < 4; ++k) pp[r][k] += __shfl_xor(pp[r][k], m);

  float4 bp4 = *(const float4*)bpool;
  float bp[4] = {bp4.x, bp4.y, bp4.z, bp4.w};
  float sv[4][4];
#pragma unroll
  for (int r = 0; r < 4; ++r) {
    float p[4];
#pragma unroll
    for (int k = 0; k < 4; ++k) p[k] = pp[r][k] + bp[k];
    float mx = fmaxf(fmaxf(p[0], p[1]), fmaxf(p[2], p[3]));
    float e0 = expf(p[0] - mx), e1 = expf(p[1] - mx), e2 = expf(p[2] - mx), e3 = expf(p[3] - mx);
    float inv = 1.f / (e0 + e1 + e2 + e3);
    float valid = (g4 * 4 + r < nrows) ? 1.f : 0.f;
    sv[r][0] = e0 * inv * valid; sv[r][1] = e1 * inv * valid;
    sv[r][2] = e2 * inv * valid; sv[r][3] = e3 * inv * valid;
  }

  // write s
  {
    int rW = li >> 2, kW = li & 3;
    if (g4 * 4 + rW < nrows) {
      int node = node0 + g4 * 4 + rW;
      float val = 0.f;
#pragma unroll
      for (int rr = 0; rr < 4; ++rr)
#pragma unroll
        for (int kk = 0; kk < 4; ++kk)
          if (li == rr * 4 + kk) val = sv[rr][kk];
      s_out[node * 4 + kW] = val;
    }
  }

  // ss[b][k1][k2]
  {
    int k1 = li >> 2, k2 = li & 3;
    float a1[4], a2[4];
#pragma unroll
    for (int rr = 0; rr < 4; ++rr) {
      float v1 = 0.f, v2 = 0.f;
#pragma unroll
      for (int kk = 0; kk < 4; ++kk) {
        if (k1 == kk) v1 = sv[rr][kk];
        if (k2 == kk) v2 = sv[rr][kk];
      }
      a1[rr] = v1; a2[rr] = v2;
    }
    float ssv = a1[0] * a2[0] + a1[1] * a2[1] + a1[2] * a2[2] + a1[3] * a2[3];
    atomicAdd(&ssL[li], ssv);
  }

  // den += deg * ||s||^2
  if (li == 0) {
    float dent = 0.f;
#pragma unroll
    for (int rr = 0; rr < 4; ++rr) {
      int rowg = g4 * 4 + rr;
      if (rowg < nrows) {
        float dg = (float)count[node0 + rowg];
        dent += dg * (sv[rr][0] * sv[rr][0] + sv[rr][1] * sv[rr][1] +
                      sv[rr][2] * sv[rr][2] + sv[rr][3] * sv[rr][3]);
      }
    }
    atomicAdd(&denL, dent);
  }

  // out[k][c] += s[r][k]*h[r][c]
  float po[4][8];
#pragma unroll
  for (int k = 0; k < 4; ++k)
#pragma unroll
    for (int c = 0; c < 8; ++c) po[k][c] = 0.f;
#pragma unroll
  for (int k = 0; k < 4; ++k)
#pragma unroll
    for (int rr = 0; rr < 4; ++rr)
#pragma unroll
      for (int c = 0; c < 8; ++c) po[k][c] = fmaf(sv[rr][k], h[rr][c], po[k][c]);
#pragma unroll
  for (int k = 0; k < 4; ++k)
#pragma unroll
    for (int c = 0; c < 8; ++c) {
      po[k][c] += __shfl_xor(po[k][c], 16);
      po[k][c] += __shfl_xor(po[k][c], 32);
    }
  if ((t & 63) < 16) {
#pragma unroll
    for (int k = 0; k < 4; ++k)
#pragma unroll
      for (int c = 0; c < 8; ++c)
        atomicAdd(&outL[k][c0 + (c & 3) + (c >> 2) * 64], po[k][c]);
  }

  __syncthreads();
  for (int i = t; i < KC * HID; i += 256)
    atomicAdd(&out_pool[bG * KC * HID + i], ((const float*)outL)[i]);
  if (t < 16) atomicAdd(&ss_g[bG * 16 + t], ssL[t]);
  if (t == 0) atomicAdd(&den_g[bG], denL);
}

// ---------------------------------------------------------------- K4: out_adj[b] = sum_n s[n] (x) t[n]  (4-way unroll)
__global__ __launch_bounds__(256) void k_adj2(const int* __restrict__ count,
                                              const int* __restrict__ rowptr,
                                              const int* __restrict__ csr,
                                              const float* __restrict__ s,
                                              float* __restrict__ adjraw) {
  __shared__ float accL[4][2][16];  // [wave][graph-within-block][k1*4+k2]
  const int t = threadIdx.x;
  if (t < 128) ((float*)accL)[t] = 0.f;
  __syncthreads();
  const int node = blockIdx.x * 256 + t;
  const int g0 = (blockIdx.x * 256) / BLK;
  if (node < NN) {
    const int gi = node / BLK - g0;  // 0 or 1
    const int deg = count[node];
    const int* sl = csr + rowptr[node];
    float A0 = 0.f, A1 = 0.f, A2 = 0.f, A3 = 0.f;
    float B0 = 0.f, B1 = 0.f, B2 = 0.f, B3 = 0.f;
    float C0 = 0.f, C1 = 0.f, C2 = 0.f, C3 = 0.f;
    float D0 = 0.f, D1 = 0.f, D2 = 0.f, D3 = 0.f;
    int e = 0;
    for (; e + 4 <= deg; e += 4) {
      int s0 = sl[e + 0], s1 = sl[e + 1], s2 = sl[e + 2], s3 = sl[e + 3];
      float4 v0 = *(const float4*)(s + (size_t)s0 * 4);
      float4 v1 = *(const float4*)(s + (size_t)s1 * 4);
      float4 v2 = *(const float4*)(s + (size_t)s2 * 4);
      float4 v3 = *(const float4*)(s + (size_t)s3 * 4);
      A0 += v0.x; A1 += v0.y; A2 += v0.z; A3 += v0.w;
      B0 += v1.x; B1 += v1.y; B2 += v1.z; B3 += v1.w;
      C0 += v2.x; C1 += v2.y; C2 += v2.z; C3 += v2.w;
      D0 += v3.x; D1 += v3.y; D2 += v3.z; D3 += v3.w;
    }
    for (; e < deg; ++e) {
      float4 v0 = *(const float4*)(s + (size_t)sl[e] * 4);
      A0 += v0.x; A1 += v0.y; A2 += v0.z; A3 += v0.w;
    }
    float t0 = A0 + B0 + C0 + D0;
    float t1 = A1 + B1 + C1 + D1;
    float t2 = A2 + B2 + C2 + D2;
    float t3 = A3 + B3 + C3 + D3;
    float4 sn = *(const float4*)(s + (size_t)node * 4);
    float* base = accL[t >> 6][gi];
#pragma unroll
    for (int i = 0; i < 16; ++i) {
      int idx = (i + t) & 15;  // stagger: 4-way instead of 64-way contention
      int hi = idx >> 2, lo = idx & 3;
      float a = (hi == 0) ? sn.x : (hi == 1) ? sn.y : (hi == 2) ? sn.z : sn.w;
      float b = (lo == 0) ? t0 : (lo == 1) ? t1 : (lo == 2) ? t2 : t3;
      atomicAdd(base + idx, a * b);
    }
  }
  __syncthreads();
  if (t < 32) {
    int gi = t >> 4, i = t & 15, gg = g0 + gi;
    if (gg < NB) {
      float v = accL[0][gi][i] + accL[1][gi][i] + accL[2][gi][i] + accL[3][gi][i];
      atomicAdd(&adjraw[gg * 16 + i], v);
    }
  }
}

// ---------------------------------------------------------------- K5a: per-graph tail
__global__ __launch_bounds__(128) void k_graph(
    const float* __restrict__ out_pool, const float* __restrict__ adjraw,
    const float* __restrict__ den_g, const float* __restrict__ ss_g,
    const float* __restrict__ Wrel3, const float* __restrict__ brel3,
    const float* __restrict__ Wroot3, const float* __restrict__ Wlin1,
    const float* __restrict__ blin1, const float* __restrict__ Wlin2,
    const float* __restrict__ blin2, float* __restrict__ d_out,
    float* __restrict__ scratch) {
  const int b = blockIdx.x, t = threadIdx.x;
  __shared__ float adjL[16], adjnL[16], dL[4];
  __shared__ float osL[128], msL[128], x2mL[128], x3L[128];
  if (t < 16) adjL[t] = adjraw[b * 16 + t];
  __syncthreads();
  if (t < 4) {
    float srow = 0.f;
#pragma unroll
    for (int l = 0; l < 4; ++l)
      if (l != t) srow += adjL[t * 4 + l];
    dL[t] = sqrtf(srow) + 1e-15f;
  }
  __syncthreads();
  if (t < 16) {
    int k1 = t >> 2, k2 = t & 3;
    float az = (k1 == k2) ? 0.f : adjL[t];
    float an = az / (dL[k2] * dL[k1]);
    adjnL[t] = an;
    d_out[400018 + b * 16 + t] = an;
  }
  __syncthreads();
  float o0 = out_pool[b * 512 + 0 * 128 + t];
  float o1 = out_pool[b * 512 + 1 * 128 + t];
  float o2 = out_pool[b * 512 + 2 * 128 + t];
  float o3 = out_pool[b * 512 + 3 * 128 + t];
  float m0 = adjnL[0] * o0 + adjnL[1] * o1 + adjnL[2] * o2 + adjnL[3] * o3;
  float m1 = adjnL[4] * o0 + adjnL[5] * o1 + adjnL[6] * o2 + adjnL[7] * o3;
  float m2 = adjnL[8] * o0 + adjnL[9] * o1 + adjnL[10] * o2 + adjnL[11] * o3;
  float m3 = adjnL[12] * o0 + adjnL[13] * o1 + adjnL[14] * o2 + adjnL[15] * o3;
  osL[t] = o0 + o1 + o2 + o3;
  msL[t] = m0 + m1 + m2 + m3;
  __syncthreads();
  float accc = brel3[t];
  for (int j = 0; j < 128; ++j)
    accc += 0.25f * (msL[j] * Wrel3[j * 128 + t] + osL[j] * Wroot3[j * 128 + t]);
  x2mL[t] = accc;
  __syncthreads();
  float a2 = blin1[t];
  for (int j = 0; j < 128; ++j) a2 += x2mL[j] * Wlin1[j * 128 + t];
  x3L[t] = fmaxf(a2, 0.f);
  __syncthreads();
  if (t < 2) {
    float lg = blin2[t];
    for (int j = 0; j < 128; ++j) lg += x3L[j] * Wlin2[j * 2 + t];
    scratch[b * 2 + t] = lg;
  }
  if (t == 0) {
    float tr = adjL[0] + adjL[5] + adjL[10] + adjL[15];
    scratch[16 + b] = tr / den_g[b];
    float n2 = 0.f;
    for (int i = 0; i < 16; ++i) { float v = ss_g[b * 16 + i]; n2 += v * v; }
    float nn = sqrtf(n2);
    float od = 0.f;
    for (int i = 0; i < 16; ++i) {
      float v = ss_g[b * 16 + i] / nn - (((i >> 2) == (i & 3)) ? 0.5f : 0.f);
      od += v * v;
    }
    scratch[24 + b] = sqrtf(od);
  }
}

// ---------------------------------------------------------------- K5b: losses + log_softmax
__global__ void k_final(const float* __restrict__ scratch, float* __restrict__ d_out) {
  if (threadIdx.x == 0 && blockIdx.x == 0) {
    float mc = 0.f, oo = 0.f;
    for (int b = 0; b < NB; ++b) { mc += scratch[16 + b]; oo += scratch[24 + b]; }
    d_out[16] = -(mc / (float)NB);
    d_out[17] = oo / (float)NB;
    for (int b = 0; b < NB; ++b) {
      float l0 = scratch[2 * b], l1 = scratch[2 * b + 1];
      float m = fmaxf(l0, l1);
      float lse = m + logf(expf(l0 - m) + expf(l1 - m));
      d_out[2 * b] = l0 - lse;
      d_out[2 * b + 1] = l1 - lse;
    }
  }
}

// ---------------------------------------------------------------- launch
extern "C" void kernel_launch(void* const* d_in, const int* in_sizes, int n_in,
                              void* d_out, int out_size, void* d_ws, size_t ws_size,
                              hipStream_t stream) {
  (void)in_sizes; (void)n_in; (void)out_size; (void)ws_size;
  const float* x      = (const float*)d_in[0];
  const int*   ei     = (const int*)d_in[1];
  const float* Wroot1 = (const float*)d_in[3];
  const float* Wrel1  = (const float*)d_in[4];
  const float* brel1  = (const float*)d_in[5];
  const float* Wpool  = (const float*)d_in[6];
  const float* bpool  = (const float*)d_in[7];
  const float* Wrel3  = (const float*)d_in[8];
  const float* brel3  = (const float*)d_in[9];
  const float* Wroot3 = (const float*)d_in[10];
  const float* Wlin1  = (const float*)d_in[11];
  const float* blin1  = (const float*)d_in[12];
  const float* Wlin2  = (const float*)d_in[13];
  const float* blin2  = (const float*)d_in[14];
  float* out = (float*)d_out;

  char* ws = (char*)d_ws;
  float*  out_pool = (float*)(ws + 0);          //  16384 B (memset)
  float*  ss_g     = (float*)(ws + 16384);      //    512 B (memset)
  float*  adjraw   = (float*)(ws + 16896);      //    512 B (memset)
  float*  den_g    = (float*)(ws + 17408);      //     32 B (memset)
  float*  scratch  = (float*)(ws + 17440);      //    128 B (memset)
  int*    sbcnt    = (int*)(ws + 17568);        //   1568 B (memset)
  int*    sbbase   = (int*)(ws + 19136);        //   1600 B
  int*    count    = (int*)(ws + 20736);        // 400000 B
  int*    rowptr   = (int*)(ws + 420736);       // 400016 B
  ushort* Wt       = (ushort*)(ws + 820752);    //  65536 B [128][256]
  int*    csr      = (int*)(ws + 886288);       // 6400000 B [E]
  ushort* xb       = (ushort*)(ws + 7286288);   // 25600000 B [N][128] bf16
  ushort* aggb     = (ushort*)(ws + 32886288);  // 25600000 B [N][128] bf16
  uint*   gbuf     = (uint*)(ws + 58486288);    // 8028160 B
  ushort* hbuf     = (ushort*)(ws + 66514448);  // 25600000 B [N][128] bf16

  hipMemsetAsync(ws, 0, 19136, stream);
  k_prep_x<<<12500, 256, 0, stream>>>((const float4*)x, xb);
  k_prep_w<<<128, 256, 0, stream>>>(Wrel1, Wroot1, Wt);
  k_bucket2<<<196, 256, 0, stream>>>(ei, sbcnt, gbuf);
  k_scan392<<<1, 512, 0, stream>>>(sbcnt, sbbase);
  k_csr_tile<<<NBIN, 256, 0, stream>>>(gbuf, sbcnt, sbbase, rowptr, count, csr);
  k_agg2<<<8 * ((BLK + 7) / 8), 256, 0, stream>>>(xb, count, rowptr, csr, aggb);
  k_gemm<<<NB * CHUNKS, 256, 0, stream>>>(aggb, xb, Wt, brel1, hbuf);
  k_epi<<<NB * CHUNKS, 256, 0, stream>>>(hbuf, Wpool, bpool, count, out + 18,
                                         out_pool, ss_g, den_g);
  k_adj2<<<(NN + 255) / 256, 256, 0, stream>>>(count, rowptr, csr, out + 18, adjraw);
  k_graph<<<NB, 128, 0, stream>>>(out_pool, adjraw, den_g, ss_g, Wrel3, brel3, Wroot3,
                                  Wlin1, blin1, Wlin2, blin2, out, scratch);
  k_final<<<1, 64, 0, stream>>>(scratch, out);
}

// Round 16
// 206.086 us; speedup vs baseline: 1.4589x; 1.0182x over previous
//
#include <hip/hip_runtime.h>

// Problem constants (fixed by the reference)
#define NN     100000      // nodes
#define EE     1600000     // edges
#define NB     8           // graphs
#define BLK    12500       // nodes per graph
#define HID    128
#define KC     4
#define CHUNKS 196         // ceil(12500/64)
#define NTILE  49          // dst-ranges of 256 nodes per graph
#define NBIN   392         // 8 graphs x 49 tiles
#define GCAPS  5120        // per-bin capacity (mean 4081, sigma ~64)

typedef __attribute__((ext_vector_type(8))) short bf16x8;
typedef __attribute__((ext_vector_type(4))) float f32x4;

__device__ __forceinline__ ushort f2bf(float f) {
  uint u = __float_as_uint(f);
  return (ushort)((u + 0x7FFFu + ((u >> 16) & 1u)) >> 16);  // RNE
}
__device__ __forceinline__ float bf2f(ushort h) {
  return __uint_as_float(((uint)h) << 16);
}

#define GLL16(g, l) \
  __builtin_amdgcn_global_load_lds((const __attribute__((address_space(1))) void*)(g), \
                                   (__attribute__((address_space(3))) void*)(l), 16, 0, 0)

// ---------------------------------------------------------------- K0a: x -> bf16
__global__ __launch_bounds__(256) void k_prep_x(const float4* __restrict__ x4,
                                                ushort* __restrict__ xb) {
  int i = blockIdx.x * 256 + threadIdx.x;  // 3.2M float4s exactly
  float4 v = x4[i];
  ushort4 r;
  r.x = f2bf(v.x); r.y = f2bf(v.y); r.z = f2bf(v.z); r.w = f2bf(v.w);
  *(ushort4*)(xb + (size_t)i * 4) = r;
}

// ---------------------------------------------------------------- K0b: Wt[col][k], k<128 = Wrel1, k>=128 = Wroot1
__global__ __launch_bounds__(256) void k_prep_w(const float* __restrict__ Wrel1,
                                                const float* __restrict__ Wroot1,
                                                ushort* __restrict__ Wt) {
  int col = blockIdx.x, k = threadIdx.x;
  float v = (k < 128) ? Wrel1[k * 128 + col] : Wroot1[(k - 128) * 128 + col];
  Wt[col * 256 + k] = f2bf(v);
}

// ---------------------------------------------------------------- K1a: edges -> 392 (graph, dst-range) sub-buckets
__global__ __launch_bounds__(256) void k_bucket2(const int* __restrict__ ei,
                                                 int* __restrict__ sbcnt,
                                                 uint* __restrict__ gbuf) {
  __shared__ uint stage[8192];
  __shared__ int cnt[NBIN], start[NBIN + 1], rbase[NBIN];
  __shared__ int gtot[8], gb[8];
  const int t = threadIdx.x;
  for (int b = t; b < NBIN; b += 256) cnt[b] = 0;
  __syncthreads();
  const int e0 = blockIdx.x * 8192;
  uint pk[32]; int br[32];
#pragma unroll
  for (int i = 0; i < 32; ++i) {
    int e = e0 + i * 256 + t;
    bool val = (e < EE);
    int src = 0, dst = 0;
    if (val) {
      src = __builtin_nontemporal_load(ei + e);
      dst = __builtin_nontemporal_load(ei + EE + e);
    }
    int g = dst / BLK;
    int dl = dst - g * BLK;
    int sl = src - g * BLK;
    int bin = g * NTILE + (dl >> 8);
    pk[i] = ((uint)sl << 16) | (uint)dl;
    br[i] = val ? ((bin << 14) | atomicAdd(&cnt[bin], 1)) : -1;
  }
  __syncthreads();
  if (t < 8) {
    int s = 0;
    for (int k = 0; k < NTILE; ++k) s += cnt[t * NTILE + k];
    gtot[t] = s;
  }
  __syncthreads();
  if (t == 0) {
    int s = 0;
    for (int g = 0; g < 8; ++g) { gb[g] = s; s += gtot[g]; }
    start[NBIN] = s;
  }
  __syncthreads();
  if (t < 8) {
    int run = gb[t];
    for (int k = 0; k < NTILE; ++k) { start[t * NTILE + k] = run; run += cnt[t * NTILE + k]; }
  }
  __syncthreads();
  for (int b = t; b < NBIN; b += 256) rbase[b] = atomicAdd(&sbcnt[b], cnt[b]);
#pragma unroll
  for (int i = 0; i < 32; ++i) {
    if (br[i] >= 0) {
      int bin = br[i] >> 14, rank = br[i] & 16383;
      stage[start[bin] + rank] = pk[i];
    }
  }
  __syncthreads();
  // per-bin segmented flush
  for (int b = t; b < NBIN; b += 256) {
    const int n = cnt[b];
    const int s0 = start[b];
    uint* dst = gbuf + (size_t)b * GCAPS + rbase[b];
    for (int i = 0; i < n; ++i) dst[i] = stage[s0 + i];
  }
}

// ---------------------------------------------------------------- K1b: exclusive scan of bin sizes
__global__ __launch_bounds__(512) void k_scan392(const int* __restrict__ sbcnt,
                                                 int* __restrict__ sbbase) {
  __shared__ int sd[512];
  const int t = threadIdx.x;
  int v = (t < NBIN) ? sbcnt[t] : 0;
  sd[t] = v;
  __syncthreads();
  for (int s = 1; s < 512; s <<= 1) {
    int x = (t >= s) ? sd[t - s] : 0;
    __syncthreads();
    sd[t] += x;
    __syncthreads();
  }
  if (t < NBIN) sbbase[t] = sd[t] - v;
}

// ---------------------------------------------------------------- K1c: per-bin LDS counting sort -> dense CSR segment + rowptr + count
__global__ __launch_bounds__(256) void k_csr_tile(const uint* __restrict__ gbuf,
                                                  const int* __restrict__ sbcnt,
                                                  const int* __restrict__ sbbase,
                                                  int* __restrict__ rowptr,
                                                  int* __restrict__ count,
                                                  int* __restrict__ csr) {
  const int g = blockIdx.x & 7;     // XCD-local per graph
  const int tile = blockIdx.x >> 3; // 0..48
  const int bin = g * NTILE + tile;
  const int m = sbcnt[bin];
  const int base = sbbase[bin];
  const int n0t = tile * 256;
  const int nt = min(256, BLK - n0t);
  __shared__ uint ent[GCAPS];
  __shared__ ushort srt[GCAPS];
  __shared__ int cnt[256], scn[256], cur[256];
  const int t = threadIdx.x;
  cnt[t] = 0;
  __syncthreads();
  const uint* buf = gbuf + (size_t)bin * GCAPS;
  for (int i = t; i < m; i += 256) {
    uint pk = buf[i];
    ent[i] = pk;
    atomicAdd(&cnt[(int)(pk & 0xFFFFu) - n0t], 1);
  }
  __syncthreads();
  int v = cnt[t];
  scn[t] = v;
  __syncthreads();
  for (int s = 1; s < 256; s <<= 1) {
    int x = (t >= s) ? scn[t - s] : 0;
    __syncthreads();
    scn[t] += x;
    __syncthreads();
  }
  int excl = scn[t] - v;
  cur[t] = excl;
  if (t < nt) {
    rowptr[g * BLK + n0t + t] = base + excl;
    count[g * BLK + n0t + t] = v;
  }
  __syncthreads();
  for (int i = t; i < m; i += 256) {
    uint pk = ent[i];
    int p = atomicAdd(&cur[(int)(pk & 0xFFFFu) - n0t], 1);
    srt[p] = (ushort)(pk >> 16);
  }
  __syncthreads();
  const int nb = g * BLK;
  for (int i = t; i < m; i += 256)
    csr[base + i] = nb + (int)srt[i];  // dense coalesced
}

// ---------------------------------------------------------------- K2: agg[n] = sum_{e: dst=n} x[src]
// R16: masked full-width batches — ALWAYS ceil(deg/8) batches of 8 loads in
// flight; out-of-range slots redirect to a zero row (no serialized remainder
// loop, which cost ~1200 dependent-latency cycles/node in R15).
__global__ __launch_bounds__(256) void k_agg2(const ushort* __restrict__ xb,
                                              const int* __restrict__ count,
                                              const int* __restrict__ rowptr,
                                              const int* __restrict__ csr,
                                              const ushort* __restrict__ zrow,
                                              ushort* __restrict__ aggb) {
  const int xg = blockIdx.x & 7;
  const int j = blockIdx.x >> 3;
  const int half = threadIdx.x >> 5;  // 8 half-waves = 8 nodes per block
  const int lane = threadIdx.x & 31;
  const int ln = j * 8 + half;
  if (ln >= BLK) return;
  const int node = xg * BLK + ln;
  const int deg = count[node];
  const int* sl = csr + rowptr[node];
  int idx0 = (lane < deg) ? sl[lane] : 0;
  int idx1 = (32 + lane < deg) ? sl[32 + lane] : 0;
  const ushort* zr = zrow + lane * 4;

  float acc[8][4];
#pragma unroll
  for (int q = 0; q < 8; ++q)
#pragma unroll
    for (int c = 0; c < 4; ++c) acc[q][c] = 0.f;

  const int nb8 = (deg + 7) >> 3;
  for (int b = 0; b < nb8; ++b) {
    const int e = b * 8;
    const ushort* ps[8];
#pragma unroll
    for (int q = 0; q < 8; ++q) {
      int ee = e + q;
      int si = (ee < 32) ? __shfl(idx0, ee, 32)
             : ((ee < 64) ? __shfl(idx1, ee - 32, 32)
                          : ((ee < deg) ? sl[ee] : 0));
      ps[q] = (ee < deg) ? (xb + (size_t)si * HID + lane * 4) : zr;
    }
    ushort4 v[8];
#pragma unroll
    for (int q = 0; q < 8; ++q) v[q] = *(const ushort4*)ps[q];
#pragma unroll
    for (int q = 0; q < 8; ++q) {
      acc[q][0] += bf2f(v[q].x); acc[q][1] += bf2f(v[q].y);
      acc[q][2] += bf2f(v[q].z); acc[q][3] += bf2f(v[q].w);
    }
  }

  float r0 = 0.f, r1 = 0.f, r2 = 0.f, r3 = 0.f;
#pragma unroll
  for (int q = 0; q < 8; ++q) { r0 += acc[q][0]; r1 += acc[q][1]; r2 += acc[q][2]; r3 += acc[q][3]; }
  ushort4 r;
  r.x = f2bf(r0); r.y = f2bf(r1); r.z = f2bf(r2); r.w = f2bf(r3);
  *(ushort4*)(aggb + (size_t)node * HID + lane * 4) = r;
}

// ---------------------------------------------------------------- K3a: GEMM half — stage A (DMA) + MFMA + bias/relu -> hbuf (dense bf16)
__global__ __launch_bounds__(256) void k_gemm(
    const ushort* __restrict__ aggb, const ushort* __restrict__ xb,
    const ushort* __restrict__ Wt, const float* __restrict__ brel1,
    ushort* __restrict__ hbuf) {
  __shared__ ushort Aag_s[64][128];  // 16 KB, linear (DMA dest)
  __shared__ ushort Ax_s[64][128];   // 16 KB, linear (DMA dest)
  __shared__ ushort hLb[64][136];    // h tile bf16 (pad 136)

  const int t = threadIdx.x;
  const int bi = blockIdx.x;
  const int bG = bi & 7;
  const int chunk = bi >> 3;
  const int node0 = bG * BLK + chunk * 64;
  int nrows = BLK - chunk * 64;
  if (nrows > 64) nrows = 64;

  const int w = t >> 6;
  const int l = t & 63;

  // async stage: 8 global_load_lds per wave (4 agg + 4 x tiles)
  {
    const int sub = l >> 4;
    const int c16 = l & 15;
#pragma unroll
    for (int i = 0; i < 4; ++i) {
      const int j = w * 4 + i;
      const int row = j * 4 + sub;
      const int rs = (row < nrows) ? row : (nrows - 1);
      const int boff = (c16 * 16) ^ ((row & 7) << 4);
      const ushort* ga = aggb + (size_t)(node0 + rs) * HID + (boff >> 1);
      const ushort* gx = xb + (size_t)(node0 + rs) * HID + (boff >> 1);
      GLL16(ga, &Aag_s[j * 4][0]);
      GLL16(gx, &Ax_s[j * 4][0]);
    }
  }

  const int m16 = l & 15;
  const int gq = l >> 4;

  bf16x8 Breg[8][2];
#pragma unroll
  for (int kt = 0; kt < 8; ++kt)
#pragma unroll
    for (int fc = 0; fc < 2; ++fc)
      Breg[kt][fc] =
          *(const bf16x8*)(Wt + (size_t)(32 * w + 16 * fc + m16) * 256 + kt * 32 + 8 * gq);

  f32x4 acc[4][2];
#pragma unroll
  for (int fr = 0; fr < 4; ++fr)
#pragma unroll
    for (int fc = 0; fc < 2; ++fc) acc[fr][fc] = (f32x4){0.f, 0.f, 0.f, 0.f};

  asm volatile("s_waitcnt vmcnt(0)" ::: "memory");
  __syncthreads();

#pragma unroll
  for (int kt = 0; kt < 8; ++kt) {
    const int k4 = kt & 3;
    bf16x8 af[4];
#pragma unroll
    for (int fr = 0; fr < 4; ++fr) {
      const int r = 16 * fr + m16;
      const int ci = (k4 * 32 + gq * 8) ^ ((r & 7) << 3);
      af[fr] = (kt < 4) ? *(const bf16x8*)&Aag_s[r][ci]
                        : *(const bf16x8*)&Ax_s[r][ci];
    }
#pragma unroll
    for (int fr = 0; fr < 4; ++fr)
#pragma unroll
      for (int fc = 0; fc < 2; ++fc)
        acc[fr][fc] = __builtin_amdgcn_mfma_f32_16x16x32_bf16(af[fr], Breg[kt][fc],
                                                              acc[fr][fc], 0, 0, 0);
  }

  const float bc0 = brel1[32 * w + m16];
  const float bc1 = brel1[32 * w + 16 + m16];
#pragma unroll
  for (int fr = 0; fr < 4; ++fr)
#pragma unroll
    for (int fc = 0; fc < 2; ++fc)
#pragma unroll
      for (int r = 0; r < 4; ++r)
        hLb[16 * fr + 4 * gq + r][32 * w + 16 * fc + m16] =
            f2bf(fmaxf(acc[fr][fc][r] + (fc ? bc1 : bc0), 0.f));
  __syncthreads();

  // dense h store: thread t -> row t>>2, 64 B chunk (t&3)
  {
    const int row = t >> 2;
    const int ch = (t & 3) * 32;
    if (row < nrows) {
      ushort* dst = hbuf + (size_t)(node0 + row) * HID + ch;
      const ushort* src = &hLb[row][ch];
#pragma unroll
      for (int q = 0; q < 4; ++q)
        *(bf16x8*)(dst + q * 8) = *(const bf16x8*)(src + q * 8);
    }
  }
}

// ---------------------------------------------------------------- K3b: epilogue half — read h, softmax + pooled reductions
__global__ __launch_bounds__(256) void k_epi(
    const ushort* __restrict__ hbuf, const float* __restrict__ Wpool,
    const float* __restrict__ bpool, const int* __restrict__ count,
    float* __restrict__ s_out, float* __restrict__ out_pool,
    float* __restrict__ ss_g, float* __restrict__ den_g) {
  __shared__ ushort hLb[64][136];
  __shared__ float outL[KC][HID];
  __shared__ float ssL[16];
  __shared__ float denL;

  const int t = threadIdx.x;
  const int bi = blockIdx.x;
  const int bG = bi & 7;
  const int chunk = bi >> 3;
  const int node0 = bG * BLK + chunk * 64;
  int nrows = BLK - chunk * 64;
  if (nrows > 64) nrows = 64;

  // dense h load: thread t -> row t>>2, 64 B chunk (t&3)
  {
    const int row = t >> 2;
    const int ch = (t & 3) * 32;
    const int rs = (row < nrows) ? row : (nrows - 1);
    const ushort* src = hbuf + (size_t)(node0 + rs) * HID + ch;
    ushort* dst = &hLb[row][ch];
#pragma unroll
    for (int q = 0; q < 4; ++q)
      *(bf16x8*)(dst + q * 8) = *(const bf16x8*)(src + q * 8);
  }

  for (int i = t; i < KC * HID; i += 256) ((float*)outL)[i] = 0.f;
  if (t < 16) ssL[t] = 0.f;
  if (t == 0) denL = 0.f;
  __syncthreads();

  const int g4 = t >> 4;
  const int c0 = (t & 15) << 2;
  const int li = t & 15;

  float h[4][8];
#pragma unroll
  for (int r = 0; r < 4; ++r) {
    ushort4 v0 = *(const ushort4*)&hLb[g4 * 4 + r][c0];
    ushort4 v1 = *(const ushort4*)&hLb[g4 * 4 + r][c0 + 64];
    h[r][0] = bf2f(v0.x); h[r][1] = bf2f(v0.y); h[r][2] = bf2f(v0.z); h[r][3] = bf2f(v0.w);
    h[r][4] = bf2f(v1.x); h[r][5] = bf2f(v1.y); h[r][6] = bf2f(v1.z); h[r][7] = bf2f(v1.w);
  }

  // pooling head: p = h @ Wpool
  float wp[8][4];
#pragma unroll
  for (int j = 0; j < 8; ++j) {
    int col = c0 + (j & 3) + (j >> 2) * 64;
    float4 v = *(const float4*)(Wpool + col * 4);
    wp[j][0] = v.x; wp[j][1] = v.y; wp[j][2] = v.z; wp[j][3] = v.w;
  }
  float pp[4][4];
#pragma unroll
  for (int r = 0; r < 4; ++r)
#pragma unroll
    for (int k = 0; k < 4; ++k) pp[r][k] = 0.f;
#pragma unroll
  for (int r = 0; r < 4; ++r)
#pragma unroll
    for (int j = 0; j < 8; ++j)
#pragma unroll
      for (int k = 0; k < 4; ++k) pp[r][k] = fmaf(h[r][j], wp[j][k], pp[r][k]);
#pragma unroll
  for (int m = 1; m <= 8; m <<= 1)
#pragma unroll
    for (int r = 0; r < 4; ++r)
#pragma unroll
      for (int k = 0; k < 4; ++k) pp[r][k] += __shfl_xor(pp[r][k], m);

  float4 bp4 = *(const float4*)bpool;
  float bp[4] = {bp4.x, bp4.y, bp4.z, bp4.w};
  float sv[4][4];
#pragma unroll
  for (int r = 0; r < 4; ++r) {
    float p[4];
#pragma unroll
    for (int k = 0; k < 4; ++k) p[k] = pp[r][k] + bp[k];
    float mx = fmaxf(fmaxf(p[0], p[1]), fmaxf(p[2], p[3]));
    float e0 = expf(p[0] - mx), e1 = expf(p[1] - mx), e2 = expf(p[2] - mx), e3 = expf(p[3] - mx);
    float inv = 1.f / (e0 + e1 + e2 + e3);
    float valid = (g4 * 4 + r < nrows) ? 1.f : 0.f;
    sv[r][0] = e0 * inv * valid; sv[r][1] = e1 * inv * valid;
    sv[r][2] = e2 * inv * valid; sv[r][3] = e3 * inv * valid;
  }

  // write s
  {
    int rW = li >> 2, kW = li & 3;
    if (g4 * 4 + rW < nrows) {
      int node = node0 + g4 * 4 + rW;
      float val = 0.f;
#pragma unroll
      for (int rr = 0; rr < 4; ++rr)
#pragma unroll
        for (int kk = 0; kk < 4; ++kk)
          if (li == rr * 4 + kk) val = sv[rr][kk];
      s_out[node * 4 + kW] = val;
    }
  }

  // ss[b][k1][k2]
  {
    int k1 = li >> 2, k2 = li & 3;
    float a1[4], a2[4];
#pragma unroll
    for (int rr = 0; rr < 4; ++rr) {
      float v1 = 0.f, v2 = 0.f;
#pragma unroll
      for (int kk = 0; kk < 4; ++kk) {
        if (k1 == kk) v1 = sv[rr][kk];
        if (k2 == kk) v2 = sv[rr][kk];
      }
      a1[rr] = v1; a2[rr] = v2;
    }
    float ssv = a1[0] * a2[0] + a1[1] * a2[1] + a1[2] * a2[2] + a1[3] * a2[3];
    atomicAdd(&ssL[li], ssv);
  }

  // den += deg * ||s||^2
  if (li == 0) {
    float dent = 0.f;
#pragma unroll
    for (int rr = 0; rr < 4; ++rr) {
      int rowg = g4 * 4 + rr;
      if (rowg < nrows) {
        float dg = (float)count[node0 + rowg];
        dent += dg * (sv[rr][0] * sv[rr][0] + sv[rr][1] * sv[rr][1] +
                      sv[rr][2] * sv[rr][2] + sv[rr][3] * sv[rr][3]);
      }
    }
    atomicAdd(&denL, dent);
  }

  // out[k][c] += s[r][k]*h[r][c]
  float po[4][8];
#pragma unroll
  for (int k = 0; k < 4; ++k)
#pragma unroll
    for (int c = 0; c < 8; ++c) po[k][c] = 0.f;
#pragma unroll
  for (int k = 0; k < 4; ++k)
#pragma unroll
    for (int rr = 0; rr < 4; ++rr)
#pragma unroll
      for (int c = 0; c < 8; ++c) po[k][c] = fmaf(sv[rr][k], h[rr][c], po[k][c]);
#pragma unroll
  for (int k = 0; k < 4; ++k)
#pragma unroll
    for (int c = 0; c < 8; ++c) {
      po[k][c] += __shfl_xor(po[k][c], 16);
      po[k][c] += __shfl_xor(po[k][c], 32);
    }
  if ((t & 63) < 16) {
#pragma unroll
    for (int k = 0; k < 4; ++k)
#pragma unroll
      for (int c = 0; c < 8; ++c)
        atomicAdd(&outL[k][c0 + (c & 3) + (c >> 2) * 64], po[k][c]);
  }

  __syncthreads();
  for (int i = t; i < KC * HID; i += 256)
    atomicAdd(&out_pool[bG * KC * HID + i], ((const float*)outL)[i]);
  if (t < 16) atomicAdd(&ss_g[bG * 16 + t], ssL[t]);
  if (t == 0) atomicAdd(&den_g[bG], denL);
}

// ---------------------------------------------------------------- K4: out_adj — masked 8-wide batches (no serial remainder)
__global__ __launch_bounds__(256) void k_adj2(const int* __restrict__ count,
                                              const int* __restrict__ rowptr,
                                              const int* __restrict__ csr,
                                              const float* __restrict__ s,
                                              const float* __restrict__ zf,
                                              float* __restrict__ adjraw) {
  __shared__ float accL[4][2][16];  // [wave][graph-within-block][k1*4+k2]
  const int t = threadIdx.x;
  if (t < 128) ((float*)accL)[t] = 0.f;
  __syncthreads();
  const int node = blockIdx.x * 256 + t;
  const int g0 = (blockIdx.x * 256) / BLK;
  if (node < NN) {
    const int gi = node / BLK - g0;  // 0 or 1
    const int deg = count[node];
    const int* sl = csr + rowptr[node];
    float a[8][4];
#pragma unroll
    for (int q = 0; q < 8; ++q)
#pragma unroll
      for (int c = 0; c < 4; ++c) a[q][c] = 0.f;
    const int nb8 = (deg + 7) >> 3;
    for (int b = 0; b < nb8; ++b) {
      const float* p[8];
#pragma unroll
      for (int q = 0; q < 8; ++q) {
        int ee = b * 8 + q;
        int si = (ee < deg) ? sl[ee] : 0;
        p[q] = (ee < deg) ? (s + (size_t)si * 4) : zf;
      }
      float4 v[8];
#pragma unroll
      for (int q = 0; q < 8; ++q) v[q] = *(const float4*)p[q];
#pragma unroll
      for (int q = 0; q < 8; ++q) {
        a[q][0] += v[q].x; a[q][1] += v[q].y; a[q][2] += v[q].z; a[q][3] += v[q].w;
      }
    }
    float t0 = 0.f, t1 = 0.f, t2 = 0.f, t3 = 0.f;
#pragma unroll
    for (int q = 0; q < 8; ++q) { t0 += a[q][0]; t1 += a[q][1]; t2 += a[q][2]; t3 += a[q][3]; }
    float4 sn = *(const float4*)(s + (size_t)node * 4);
    float* base = accL[t >> 6][gi];
#pragma unroll
    for (int i = 0; i < 16; ++i) {
      int idx = (i + t) & 15;  // stagger: 4-way instead of 64-way contention
      int hi = idx >> 2, lo = idx & 3;
      float a1 = (hi == 0) ? sn.x : (hi == 1) ? sn.y : (hi == 2) ? sn.z : sn.w;
      float b1 = (lo == 0) ? t0 : (lo == 1) ? t1 : (lo == 2) ? t2 : t3;
      atomicAdd(base + idx, a1 * b1);
    }
  }
  __syncthreads();
  if (t < 32) {
    int gi = t >> 4, i = t & 15, gg = g0 + gi;
    if (gg < NB) {
      float v = accL[0][gi][i] + accL[1][gi][i] + accL[2][gi][i] + accL[3][gi][i];
      atomicAdd(&adjraw[gg * 16 + i], v);
    }
  }
}

// ---------------------------------------------------------------- K5a: per-graph tail
__global__ __launch_bounds__(128) void k_graph(
    const float* __restrict__ out_pool, const float* __restrict__ adjraw,
    const float* __restrict__ den_g, const float* __restrict__ ss_g,
    const float* __restrict__ Wrel3, const float* __restrict__ brel3,
    const float* __restrict__ Wroot3, const float* __restrict__ Wlin1,
    const float* __restrict__ blin1, const float* __restrict__ Wlin2,
    const float* __restrict__ blin2, float* __restrict__ d_out,
    float* __restrict__ scratch) {
  const int b = blockIdx.x, t = threadIdx.x;
  __shared__ float adjL[16], adjnL[16], dL[4];
  __shared__ float osL[128], msL[128], x2mL[128], x3L[128];
  if (t < 16) adjL[t] = adjraw[b * 16 + t];
  __syncthreads();
  if (t < 4) {
    float srow = 0.f;
#pragma unroll
    for (int l = 0; l < 4; ++l)
      if (l != t) srow += adjL[t * 4 + l];
    dL[t] = sqrtf(srow) + 1e-15f;
  }
  __syncthreads();
  if (t < 16) {
    int k1 = t >> 2, k2 = t & 3;
    float az = (k1 == k2) ? 0.f : adjL[t];
    float an = az / (dL[k2] * dL[k1]);
    adjnL[t] = an;
    d_out[400018 + b * 16 + t] = an;
  }
  __syncthreads();
  float o0 = out_pool[b * 512 + 0 * 128 + t];
  float o1 = out_pool[b * 512 + 1 * 128 + t];
  float o2 = out_pool[b * 512 + 2 * 128 + t];
  float o3 = out_pool[b * 512 + 3 * 128 + t];
  float m0 = adjnL[0] * o0 + adjnL[1] * o1 + adjnL[2] * o2 + adjnL[3] * o3;
  float m1 = adjnL[4] * o0 + adjnL[5] * o1 + adjnL[6] * o2 + adjnL[7] * o3;
  float m2 = adjnL[8] * o0 + adjnL[9] * o1 + adjnL[10] * o2 + adjnL[11] * o3;
  float m3 = adjnL[12] * o0 + adjnL[13] * o1 + adjnL[14] * o2 + adjnL[15] * o3;
  osL[t] = o0 + o1 + o2 + o3;
  msL[t] = m0 + m1 + m2 + m3;
  __syncthreads();
  float accc = brel3[t];
  for (int j = 0; j < 128; ++j)
    accc += 0.25f * (msL[j] * Wrel3[j * 128 + t] + osL[j] * Wroot3[j * 128 + t]);
  x2mL[t] = accc;
  __syncthreads();
  float a2 = blin1[t];
  for (int j = 0; j < 128; ++j) a2 += x2mL[j] * Wlin1[j * 128 + t];
  x3L[t] = fmaxf(a2, 0.f);
  __syncthreads();
  if (t < 2) {
    float lg = blin2[t];
    for (int j = 0; j < 128; ++j) lg += x3L[j] * Wlin2[j * 2 + t];
    scratch[b * 2 + t] = lg;
  }
  if (t == 0) {
    float tr = adjL[0] + adjL[5] + adjL[10] + adjL[15];
    scratch[16 + b] = tr / den_g[b];
    float n2 = 0.f;
    for (int i = 0; i < 16; ++i) { float v = ss_g[b * 16 + i]; n2 += v * v; }
    float nn = sqrtf(n2);
    float od = 0.f;
    for (int i = 0; i < 16; ++i) {
      float v = ss_g[b * 16 + i] / nn - (((i >> 2) == (i & 3)) ? 0.5f : 0.f);
      od += v * v;
    }
    scratch[24 + b] = sqrtf(od);
  }
}

// ---------------------------------------------------------------- K5b: losses + log_softmax
__global__ void k_final(const float* __restrict__ scratch, float* __restrict__ d_out) {
  if (threadIdx.x == 0 && blockIdx.x == 0) {
    float mc = 0.f, oo = 0.f;
    for (int b = 0; b < NB; ++b) { mc += scratch[16 + b]; oo += scratch[24 + b]; }
    d_out[16] = -(mc / (float)NB);
    d_out[17] = oo / (float)NB;
    for (int b = 0; b < NB; ++b) {
      float l0 = scratch[2 * b], l1 = scratch[2 * b + 1];
      float m = fmaxf(l0, l1);
      float lse = m + logf(expf(l0 - m) + expf(l1 - m));
      d_out[2 * b] = l0 - lse;
      d_out[2 * b + 1] = l1 - lse;
    }
  }
}

// ---------------------------------------------------------------- launch
extern "C" void kernel_launch(void* const* d_in, const int* in_sizes, int n_in,
                              void* d_out, int out_size, void* d_ws, size_t ws_size,
                              hipStream_t stream) {
  (void)in_sizes; (void)n_in; (void)out_size; (void)ws_size;
  const float* x      = (const float*)d_in[0];
  const int*   ei     = (const int*)d_in[1];
  const float* Wroot1 = (const float*)d_in[3];
  const float* Wrel1  = (const float*)d_in[4];
  const float* brel1  = (const float*)d_in[5];
  const float* Wpool  = (const float*)d_in[6];
  const float* bpool  = (const float*)d_in[7];
  const float* Wrel3  = (const float*)d_in[8];
  const float* brel3  = (const float*)d_in[9];
  const float* Wroot3 = (const float*)d_in[10];
  const float* Wlin1  = (const float*)d_in[11];
  const float* blin1  = (const float*)d_in[12];
  const float* Wlin2  = (const float*)d_in[13];
  const float* blin2  = (const float*)d_in[14];
  float* out = (float*)d_out;

  char* ws = (char*)d_ws;
  float*  out_pool = (float*)(ws + 0);          //  16384 B (memset)
  float*  ss_g     = (float*)(ws + 16384);      //    512 B (memset)
  float*  adjraw   = (float*)(ws + 16896);      //    512 B (memset)
  float*  den_g    = (float*)(ws + 17408);      //     32 B (memset)
  float*  scratch  = (float*)(ws + 17440);      //    128 B (memset)
  int*    sbcnt    = (int*)(ws + 17568);        //   1568 B (memset)
  ushort* zrow     = (ushort*)(ws + 19136);     //    256 B zeros (memset)
  float*  zf       = (float*)(ws + 19392);      //     16 B zeros (memset)
  int*    sbbase   = (int*)(ws + 19648);        //   1600 B
  int*    count    = (int*)(ws + 21248);        // 400000 B
  int*    rowptr   = (int*)(ws + 421248);       // 400016 B
  ushort* Wt       = (ushort*)(ws + 821264);    //  65536 B [128][256]
  int*    csr      = (int*)(ws + 886800);       // 6400000 B [E]
  ushort* xb       = (ushort*)(ws + 7286800);   // 25600000 B [N][128] bf16
  ushort* aggb     = (ushort*)(ws + 32886800);  // 25600000 B [N][128] bf16
  uint*   gbuf     = (uint*)(ws + 58486800);    // 8028160 B
  ushort* hbuf     = (ushort*)(ws + 66514960);  // 25600000 B [N][128] bf16

  hipMemsetAsync(ws, 0, 19648, stream);
  k_prep_x<<<12500, 256, 0, stream>>>((const float4*)x, xb);
  k_prep_w<<<128, 256, 0, stream>>>(Wrel1, Wroot1, Wt);
  k_bucket2<<<196, 256, 0, stream>>>(ei, sbcnt, gbuf);
  k_scan392<<<1, 512, 0, stream>>>(sbcnt, sbbase);
  k_csr_tile<<<NBIN, 256, 0, stream>>>(gbuf, sbcnt, sbbase, rowptr, count, csr);
  k_agg2<<<8 * ((BLK + 7) / 8), 256, 0, stream>>>(xb, count, rowptr, csr, zrow, aggb);
  k_gemm<<<NB * CHUNKS, 256, 0, stream>>>(aggb, xb, Wt, brel1, hbuf);
  k_epi<<<NB * CHUNKS, 256, 0, stream>>>(hbuf, Wpool, bpool, count, out + 18,
                                         out_pool, ss_g, den_g);
  k_adj2<<<(NN + 255) / 256, 256, 0, stream>>>(count, rowptr, csr, out + 18, zf, adjraw);
  k_graph<<<NB, 128, 0, stream>>>(out_pool, adjraw, den_g, ss_g, Wrel3, brel3, Wroot3,
                                  Wlin1, blin1, Wlin2, blin2, out, scratch);
  k_final<<<1, 64, 0, stream>>>(scratch, out);
}